// Round 15
// baseline (705.449 us; speedup 1.0000x reference)
//
#include <hip/hip_runtime.h>
#include <stdint.h>

#define N_TOT 100000
#define IN_CHN 1024
#define MDIM 512
#define ATT_D 128
#define NUM_GROUP 8
#define GROUP_SIZE 12500
#define SEGR 98  // rows per kbag segment

typedef __bf16 bf16x8 __attribute__((ext_vector_type(8)));
typedef float f32x4 __attribute__((ext_vector_type(4)));
typedef unsigned short u16x8 __attribute__((ext_vector_type(8)));

__device__ __forceinline__ unsigned short f2bf(float x){
  union { float f; unsigned u; } v; v.f = x;
  unsigned r = v.u + 0x7fffu + ((v.u >> 16) & 1u);
  return (unsigned short)(r >> 16);
}
__device__ __forceinline__ float bf2f(unsigned short h){
  union { unsigned u; float f; } v; v.u = ((unsigned)h) << 16; return v.f;
}
__device__ __forceinline__ void gload16(const void* g, void* l){
  __builtin_amdgcn_global_load_lds(
      (const __attribute__((address_space(1))) unsigned int*)g,
      (__attribute__((address_space(3))) unsigned int*)l, 16, 0, 0);
}

// ---------------- weight conversion f32 -> bf16 ----------------
__global__ __launch_bounds__(256) void kconv(const float* __restrict__ W1,
                                             const float* __restrict__ Wa1,
                                             unsigned short* __restrict__ W1b,
                                             unsigned short* __restrict__ Wa1b){
  int i = blockIdx.x * 256 + threadIdx.x;
  if (i < MDIM * IN_CHN) W1b[i] = f2bf(W1[i]);
  else {
    int j = i - MDIM * IN_CHN;
    if (j < ATT_D * MDIM) Wa1b[j] = f2bf(Wa1[j]);
  }
}

// ---------------- main gather+GEMM: mid = relu(tfeat[idx] @ W1b^T + b1) ----------------
// 128x128 tile, BK=32, 3-buffer pipeline with COUNTED vmcnt + raw s_barrier:
// stage(s+2) -> vmcnt(12) [stage s landed, 12 newer loads stay in flight]
// -> s_barrier -> compute(s) -> s_barrier. 72.5KB LDS -> 2 blocks/CU.
__global__ __launch_bounds__(256) void kgemm_mid(const int* __restrict__ idxf,
                                                 const float* __restrict__ tfeat,
                                                 const unsigned short* __restrict__ W1b,
                                                 const float* __restrict__ b1,
                                                 unsigned short* __restrict__ midb){
  __shared__ alignas(16) float A0[128 * 32];            // 16 KB
  __shared__ alignas(16) float A1[128 * 32];
  __shared__ alignas(16) float A2[128 * 32];
  __shared__ alignas(16) unsigned short B0[128 * 32];   // 8 KB
  __shared__ alignas(16) unsigned short B1[128 * 32];
  __shared__ alignas(16) unsigned short B2[128 * 32];
  __shared__ int gsm[128];
  int tid = threadIdx.x;
  int tile = (blockIdx.x & 7) * 391 + (blockIdx.x >> 3);   // bijective, XCD-grouped
  int bn = tile & 3, bm = tile >> 2;
  int m0 = bm * 128, n0 = bn * 128;
  if (tid < 128){ int r = m0 + tid; gsm[tid] = idxf[r < N_TOT ? r : 0]; }
  __syncthreads();

  int w = tid >> 6, l = tid & 63;
  int l16 = tid & 15, hi = (tid >> 4) & 3;
  int wm = tid >> 7, wn = (tid >> 6) & 1;

  // A staging: 4 rounds, rows q*32+w*8+(l>>3), chunk (l&7)^(l>>3) of 8x16B.
  const float* asrc[4]; int adst[4];
  #pragma unroll
  for (int q = 0; q < 4; q++){
    int rowl = q * 32 + w * 8 + (l >> 3);
    asrc[q] = tfeat + (size_t)gsm[rowl] * IN_CHN + (((l & 7) ^ (l >> 3)) << 2);
    adst[q] = (q * 32 + w * 8) * 32;
  }
  // B staging: 2 rounds, rows q*64+w*16+(l>>2), chunk (l&3)^((l>>3)&3) of 4x16B.
  const unsigned short* bsrc[2]; int bdst[2];
  #pragma unroll
  for (int q = 0; q < 2; q++){
    int rowl = q * 64 + w * 16 + (l >> 2);
    bsrc[q] = W1b + (size_t)(n0 + rowl) * IN_CHN + (((l & 3) ^ ((l >> 3) & 3)) << 3);
    bdst[q] = (q * 64 + w * 16) * 32;
  }

  f32x4 acc[4][4];
  #pragma unroll
  for (int a = 0; a < 4; a++)
    #pragma unroll
    for (int b = 0; b < 4; b++) acc[a][b] = (f32x4){0.f, 0.f, 0.f, 0.f};

  int r7 = l16 & 7;
  int b3 = (l16 >> 1) & 3;

  auto stage = [&](float* Ax, unsigned short* Bx, int s){
    #pragma unroll
    for (int q = 0; q < 4; q++) gload16(asrc[q] + s * 32, Ax + adst[q]);
    #pragma unroll
    for (int q = 0; q < 2; q++) gload16(bsrc[q] + s * 32, Bx + bdst[q]);
  };
  auto compute = [&](const float* Ax, const unsigned short* Bx){
    bf16x8 af[4], bfr[4];
    #pragma unroll
    for (int a = 0; a < 4; a++){
      int row = wm * 64 + a * 16 + l16;
      f32x4 lo  = *(const f32x4*)&Ax[row * 32 + (((2 * hi) ^ r7) << 2)];
      f32x4 hi4 = *(const f32x4*)&Ax[row * 32 + (((2 * hi + 1) ^ r7) << 2)];
      bf16x8 pk;
      pk[0] = (__bf16)lo[0]; pk[1] = (__bf16)lo[1]; pk[2] = (__bf16)lo[2]; pk[3] = (__bf16)lo[3];
      pk[4] = (__bf16)hi4[0]; pk[5] = (__bf16)hi4[1]; pk[6] = (__bf16)hi4[2]; pk[7] = (__bf16)hi4[3];
      af[a] = pk;
    }
    #pragma unroll
    for (int b = 0; b < 4; b++){
      int row = wn * 64 + b * 16 + l16;
      bfr[b] = *(const bf16x8*)&Bx[row * 32 + ((hi ^ b3) << 3)];
    }
    #pragma unroll
    for (int a = 0; a < 4; a++)
      #pragma unroll
      for (int b = 0; b < 4; b++)
        acc[a][b] = __builtin_amdgcn_mfma_f32_16x16x32_bf16(af[a], bfr[b], acc[a][b], 0, 0, 0);
  };

  float *Ac = A0, *An = A1, *Aq = A2;
  unsigned short *Bc = B0, *Bn = B1, *Bq = B2;

  stage(Ac, Bc, 0);        // 6 loads in flight
  stage(An, Bn, 1);        // 12 in flight
  for (int s = 0; s < 32; s++){
    if (s + 2 < 32) stage(Aq, Bq, s + 2);            // up to 18 in flight
    if (s < 30)      asm volatile("s_waitcnt vmcnt(12)" ::: "memory");
    else if (s == 30) asm volatile("s_waitcnt vmcnt(6)" ::: "memory");
    else              asm volatile("s_waitcnt vmcnt(0)" ::: "memory");
    __builtin_amdgcn_s_barrier();    // all threads' stage-s loads landed
    compute(Ac, Bc);
    __builtin_amdgcn_s_barrier();    // buf s free for overwrite at iter s+1
    float* ta = Ac; Ac = An; An = Aq; Aq = ta;
    unsigned short* tb = Bc; Bc = Bn; Bn = Bq; Bq = tb;
  }

  #pragma unroll
  for (int b = 0; b < 4; b++){
    int col = n0 + wn * 64 + b * 16 + l16;
    float bias = b1[col];
    #pragma unroll
    for (int a = 0; a < 4; a++){
      int rbase = m0 + wm * 64 + a * 16 + hi * 4;
      #pragma unroll
      for (int q = 0; q < 4; q++){
        int row = rbase + q;
        if (row < N_TOT){
          float v = acc[a][b][q] + bias;
          midb[(size_t)row * MDIM + col] = f2bf(fmaxf(v, 0.f));
        }
      }
    }
  }
}

// ---------------- attention MLP + fused tv: gload_lds staging, proven swizzle ----------------
__global__ __launch_bounds__(256) void kattn(const unsigned short* __restrict__ midb,
                                             const unsigned short* __restrict__ Wa1b,
                                             const float* __restrict__ ba1,
                                             const float* __restrict__ Wa2,
                                             const float* __restrict__ ba2,
                                             const float* __restrict__ Wc,
                                             float* __restrict__ lv,
                                             float* __restrict__ tv){
  __shared__ alignas(16) unsigned short Asm[128 * 64];
  __shared__ alignas(16) unsigned short Bsm[128 * 64];
  __shared__ float dsh[512];
  __shared__ float part[128][2];
  int tid = threadIdx.x;
  int m0 = blockIdx.x * 128;
  for (int i = tid; i < 512; i += 256) dsh[i] = Wc[512 + i] - Wc[i];

  int w = tid >> 6, l = tid & 63;
  int l16 = tid & 15, hi = (tid >> 4) & 3;
  int wm = tid >> 7, wn = (tid >> 6) & 1;
  int scw = (l & 7) ^ (l >> 3);

  const unsigned short *asrc[4], *bsrc[4];
  int dsto[4];
  #pragma unroll
  for (int q = 0; q < 4; q++){
    int rowl = q * 32 + w * 8 + (l >> 3);
    asrc[q] = midb + (size_t)(m0 + rowl) * MDIM + scw * 8;
    bsrc[q] = Wa1b + (size_t)rowl * MDIM + scw * 8;
    dsto[q] = (q * 32 + w * 8) * 64;
  }

  f32x4 acc[4][4];
  #pragma unroll
  for (int a = 0; a < 4; a++)
    #pragma unroll
    for (int b = 0; b < 4; b++) acc[a][b] = (f32x4){0.f, 0.f, 0.f, 0.f};
  int r7 = l16 & 7;

  int rt = tid >> 1, kh = tid & 1;
  int rt7 = rt & 7;
  float t = 0.f;

  for (int s = 0; s < 8; s++){
    __syncthreads();
    #pragma unroll
    for (int q = 0; q < 4; q++){
      gload16(asrc[q] + s * 64, &Asm[dsto[q]]);
      gload16(bsrc[q] + s * 64, &Bsm[dsto[q]]);
    }
    __syncthreads();
    #pragma unroll
    for (int ks = 0; ks < 2; ks++){
      bf16x8 af[4], bfr[4];
      #pragma unroll
      for (int a = 0; a < 4; a++){
        int row = wm * 64 + a * 16 + l16;
        af[a] = *(const bf16x8*)&Asm[row * 64 + (((ks * 4 + hi) ^ r7) << 3)];
      }
      #pragma unroll
      for (int b = 0; b < 4; b++){
        int row = wn * 64 + b * 16 + l16;
        bfr[b] = *(const bf16x8*)&Bsm[row * 64 + (((ks * 4 + hi) ^ r7) << 3)];
      }
      #pragma unroll
      for (int a = 0; a < 4; a++)
        #pragma unroll
        for (int b = 0; b < 4; b++)
          acc[a][b] = __builtin_amdgcn_mfma_f32_16x16x32_bf16(af[a], bfr[b], acc[a][b], 0, 0, 0);
    }
    #pragma unroll
    for (int j = 0; j < 4; j++){
      int gc = kh * 4 + j;
      u16x8 v = *(const u16x8*)&Asm[rt * 64 + ((gc ^ rt7) << 3)];
      int kb = s * 64 + gc * 8;
      #pragma unroll
      for (int e = 0; e < 8; e++) t += bf2f((unsigned short)v[e]) * dsh[kb + e];
    }
  }
  t += __shfl_xor(t, 1);
  if (kh == 0){
    int row = m0 + rt;
    if (row < N_TOT) tv[row] = t;
  }
  #pragma unroll
  for (int a = 0; a < 4; a++){
    #pragma unroll
    for (int q = 0; q < 4; q++){
      float v = 0.f;
      #pragma unroll
      for (int b = 0; b < 4; b++){
        int col = wn * 64 + b * 16 + l16;
        v += tanhf(acc[a][b][q] + ba1[col]) * Wa2[col];
      }
      #pragma unroll
      for (int off = 1; off < 16; off <<= 1) v += __shfl_xor(v, off);
      if (l16 == 0) part[wm * 64 + a * 16 + hi * 4 + q][wn] = v;
    }
  }
  __syncthreads();
  if (tid < 128){
    int row = m0 + tid;
    if (row < N_TOT) lv[row] = part[tid][0] + part[tid][1] + ba2[0];
  }
}

// ---------------- per-group stats + top/bottom-16 + fused softmax weights ----------------
__global__ __launch_bounds__(256) void kselect(const float* __restrict__ lv,
                                               const float* __restrict__ tv,
                                               float* __restrict__ maxlw, float* __restrict__ Zw,
                                               int* __restrict__ cand,
                                               float* __restrict__ w){
  __shared__ float keys[GROUP_SIZE];
  __shared__ float candk[4096];
  __shared__ int   candi[4096];
  __shared__ float rk[256];
  __shared__ int ri[256];
  __shared__ int rs[256];
  __shared__ float sbc;
  int g = blockIdx.x, tid = threadIdx.x;
  const float* lg = lv + (size_t)g * GROUP_SIZE;
  const float* tg = tv + (size_t)g * GROUP_SIZE;

  float mx = -1e30f;
  for (int i = tid; i < GROUP_SIZE; i += 256) mx = fmaxf(mx, lg[i]);
  rk[tid] = mx; __syncthreads();
  for (int s = 128; s > 0; s >>= 1){ if (tid < s) rk[tid] = fmaxf(rk[tid], rk[tid + s]); __syncthreads(); }
  if (tid == 0) sbc = rk[0];
  __syncthreads();
  float maxl = sbc;

  float z = 0.f;
  for (int i = tid; i < GROUP_SIZE; i += 256){
    float ez = expf(lg[i] - maxl);
    z += ez;
    keys[i] = ez * tg[i];
  }
  rk[tid] = z; __syncthreads();
  for (int s = 128; s > 0; s >>= 1){ if (tid < s) rk[tid] += rk[tid + s]; __syncthreads(); }
  if (tid == 0){ maxlw[g] = maxl; Zw[g] = rk[0]; }
  __syncthreads();
  float invZ = 1.0f / rk[0];
  for (int i = tid; i < GROUP_SIZE; i += 256)
    w[(size_t)g * GROUP_SIZE + i] = expf(lg[i] - maxl) * invZ;
  __syncthreads();

  // ---- TOP-16 ----
  {
    float tk[16]; int tix[16];
    #pragma unroll
    for (int j = 0; j < 16; j++){ tk[j] = -1e30f; tix[j] = 0x7fffffff; }
    for (int i = tid; i < GROUP_SIZE; i += 256){
      float ck = keys[i];
      if (ck > tk[15]){
        int ci = i;
        #pragma unroll
        for (int j = 0; j < 16; j++){
          bool ins = ck > tk[j];
          float nk = ins ? ck : tk[j]; int ni = ins ? ci : tix[j];
          float ok = ins ? tk[j] : ck; int oi = ins ? tix[j] : ci;
          tk[j] = nk; tix[j] = ni; ck = ok; ci = oi;
        }
      }
    }
    #pragma unroll
    for (int j = 0; j < 16; j++){ candk[tid * 16 + j] = tk[j]; candi[tid * 16 + j] = tix[j]; }
  }
  __syncthreads();
  for (int it = 0; it < 16; it++){
    float bk = -1e30f; int bi = 0x7fffffff; int bs = -1;
    for (int jj = tid; jj < 4096; jj += 256){
      float k = candk[jj]; int ix = candi[jj];
      if (k > bk || (k == bk && ix < bi)){ bk = k; bi = ix; bs = jj; }
    }
    rk[tid] = bk; ri[tid] = bi; rs[tid] = bs; __syncthreads();
    for (int s = 128; s > 0; s >>= 1){
      if (tid < s){
        if (rk[tid + s] > rk[tid] || (rk[tid + s] == rk[tid] && ri[tid + s] < ri[tid])){
          rk[tid] = rk[tid + s]; ri[tid] = ri[tid + s]; rs[tid] = rs[tid + s];
        }
      }
      __syncthreads();
    }
    if (tid == 0){ cand[g * 32 + it] = ri[0]; candk[rs[0]] = -1e30f; }
    __syncthreads();
  }

  // ---- BOTTOM-16 ----
  {
    float tk[16]; int tix[16];
    #pragma unroll
    for (int j = 0; j < 16; j++){ tk[j] = 1e30f; tix[j] = -1; }
    for (int i = tid; i < GROUP_SIZE; i += 256){
      float ck = keys[i];
      if (ck <= tk[15]){
        int ci = i;
        #pragma unroll
        for (int j = 0; j < 16; j++){
          bool ins = ck <= tk[j];   // ties: later (larger) idx goes first
          float nk = ins ? ck : tk[j]; int ni = ins ? ci : tix[j];
          float ok = ins ? tk[j] : ck; int oi = ins ? tix[j] : ci;
          tk[j] = nk; tix[j] = ni; ck = ok; ci = oi;
        }
      }
    }
    #pragma unroll
    for (int j = 0; j < 16; j++){ candk[tid * 16 + j] = tk[j]; candi[tid * 16 + j] = tix[j]; }
  }
  __syncthreads();
  for (int it = 0; it < 16; it++){
    float bk = 1e30f; int bi = -1; int bs = -1;
    for (int jj = tid; jj < 4096; jj += 256){
      float k = candk[jj]; int ix = candi[jj];
      if (k < bk || (k == bk && ix > bi)){ bk = k; bi = ix; bs = jj; }
    }
    rk[tid] = bk; ri[tid] = bi; rs[tid] = bs; __syncthreads();
    for (int s = 128; s > 0; s >>= 1){
      if (tid < s){
        if (rk[tid + s] < rk[tid] || (rk[tid + s] == rk[tid] && ri[tid + s] > ri[tid])){
          rk[tid] = rk[tid + s]; ri[tid] = ri[tid + s]; rs[tid] = rs[tid + s];
        }
      }
      __syncthreads();
    }
    if (tid == 0){ cand[g * 32 + 16 + it] = ri[0]; candk[rs[0]] = 1e30f; }
    __syncthreads();
  }
}

// ---------------- exact f32 recompute of 256 candidate rows ----------------
__global__ __launch_bounds__(256) void kexact(const int* __restrict__ idxf,
                                              const float* __restrict__ tfeat,
                                              const float* __restrict__ W1,
                                              const float* __restrict__ b1,
                                              const float* __restrict__ Wa1,
                                              const float* __restrict__ ba1,
                                              const float* __restrict__ Wa2,
                                              const float* __restrict__ ba2,
                                              const float* __restrict__ Wc,
                                              const int* __restrict__ cand,
                                              const float* __restrict__ maxlw,
                                              float* __restrict__ emid, float* __restrict__ ekey){
  __shared__ float subs[1024];
  __shared__ float midc[512];
  __shared__ float hs[128];
  __shared__ float red[256];
  __shared__ float tsh;
  int bid = blockIdx.x; int g = bid >> 5, c = bid & 31; int tid = threadIdx.x;
  int s = cand[g * 32 + c];
  int inst = idxf[g * GROUP_SIZE + s];
  ((float4*)subs)[tid] = ((const float4*)(tfeat + (size_t)inst * IN_CHN))[tid];
  __syncthreads();

  float a0 = b1[tid], a1 = b1[tid + 256];
  const float4* w0 = (const float4*)(W1 + (size_t)tid * IN_CHN);
  const float4* w1 = (const float4*)(W1 + ((size_t)tid + 256) * IN_CHN);
  const float4* s4 = (const float4*)subs;
  #pragma unroll 4
  for (int k = 0; k < 256; k++){
    float4 sv = s4[k], wva = w0[k], wvb = w1[k];
    a0 += sv.x * wva.x + sv.y * wva.y + sv.z * wva.z + sv.w * wva.w;
    a1 += sv.x * wvb.x + sv.y * wvb.y + sv.z * wvb.z + sv.w * wvb.w;
  }
  a0 = fmaxf(a0, 0.f); a1 = fmaxf(a1, 0.f);
  midc[tid] = a0; midc[tid + 256] = a1;
  size_t eo = (size_t)(g * 32 + c) * MDIM;
  emid[eo + tid] = a0; emid[eo + tid + 256] = a1;
  __syncthreads();

  if (tid < 128){
    const float4* wr = (const float4*)(Wa1 + (size_t)tid * MDIM);
    const float4* m4 = (const float4*)midc;
    float h = ba1[tid];
    #pragma unroll 4
    for (int j = 0; j < 128; j++){
      float4 mv = m4[j], wv = wr[j];
      h += mv.x * wv.x + mv.y * wv.y + mv.z * wv.z + mv.w * wv.w;
    }
    hs[tid] = tanhf(h) * Wa2[tid];
  }
  __syncthreads();

  float tp = midc[tid] * (Wc[512 + tid] - Wc[tid]) + midc[tid + 256] * (Wc[768 + tid] - Wc[256 + tid]);
  red[tid] = tp; __syncthreads();
  for (int st = 128; st > 0; st >>= 1){ if (tid < st) red[tid] += red[tid + st]; __syncthreads(); }
  if (tid == 0) tsh = red[0];
  __syncthreads();
  red[tid] = (tid < 128) ? hs[tid] : 0.f; __syncthreads();
  for (int st = 128; st > 0; st >>= 1){ if (tid < st) red[tid] += red[tid + st]; __syncthreads(); }
  if (tid == 0){
    float lval = red[0] + ba2[0];
    ekey[g * 32 + c] = expf(lval - maxlw[g]) * tsh;
  }
}

// ---------------- weighted bag-sum: 128 segments x 8 groups, partials ----------------
__global__ __launch_bounds__(256) void kbag(const unsigned short* __restrict__ midb,
                                            const float* __restrict__ w,
                                            float* __restrict__ bagp){
  __shared__ float wl[SEGR];
  int g = blockIdx.x >> 7, seg = blockIdx.x & 127, tid = threadIdx.x;
  int i0 = seg * SEGR;
  int nr = GROUP_SIZE - i0; if (nr > SEGR) nr = SEGR;
  size_t base = (size_t)g * GROUP_SIZE;
  if (tid < nr) wl[tid] = w[base + i0 + tid];
  __syncthreads();
  float a0 = 0.f, a1 = 0.f;
  const unsigned short* mp = midb + (base + i0) * MDIM + 2 * tid;
  int i = 0;
  for (; i + 2 <= nr; i += 2){
    unsigned pk0 = *(const unsigned*)(mp + (size_t)i * MDIM);
    unsigned pk1 = *(const unsigned*)(mp + (size_t)(i + 1) * MDIM);
    float w0 = wl[i], w1 = wl[i + 1];
    a0 += w0 * bf2f((unsigned short)(pk0 & 0xffff)) + w1 * bf2f((unsigned short)(pk1 & 0xffff));
    a1 += w0 * bf2f((unsigned short)(pk0 >> 16)) + w1 * bf2f((unsigned short)(pk1 >> 16));
  }
  if (i < nr){
    unsigned pk0 = *(const unsigned*)(mp + (size_t)i * MDIM);
    float w0 = wl[i];
    a0 += w0 * bf2f((unsigned short)(pk0 & 0xffff));
    a1 += w0 * bf2f((unsigned short)(pk0 >> 16));
  }
  float* dst = bagp + (size_t)blockIdx.x * MDIM + 2 * tid;
  dst[0] = a0; dst[1] = a1;
}

// ---------------- final: exact re-rank, preds, feature copy — FLOAT32 output ----------------
__global__ __launch_bounds__(256) void kfinal(const float* __restrict__ bagp,
                                              const float* __restrict__ Wc,
                                              const float* __restrict__ bc,
                                              const float* __restrict__ emid,
                                              const float* __restrict__ ekey,
                                              const int* __restrict__ cand,
                                              float* __restrict__ out){
  __shared__ float k32[32];
  __shared__ int s32[32];
  __shared__ int ordv[32];
  __shared__ float r0[256], r1[256];
  int g = blockIdx.x, tid = threadIdx.x;
  if (tid < 32){ k32[tid] = ekey[g * 32 + tid]; s32[tid] = cand[g * 32 + tid]; }
  __syncthreads();
  if (tid == 0){
    unsigned used = 0;
    for (int a = 0; a < 32; a++){
      int best = -1;
      for (int b = 0; b < 32; b++){
        if ((used >> b) & 1u) continue;
        if (best < 0 || k32[b] > k32[best] || (k32[b] == k32[best] && s32[b] < s32[best])) best = b;
      }
      used |= 1u << best;
      ordv[a] = best;
    }
  }
  float p0 = 0.f, p1 = 0.f;
  for (int j = tid; j < 512; j += 256){
    float bv = 0.f;
    for (int s2 = 0; s2 < 128; s2++) bv += bagp[(size_t)(g * 128 + s2) * MDIM + j];
    p0 += bv * Wc[j];
    p1 += bv * Wc[512 + j];
  }
  r0[tid] = p0; r1[tid] = p1; __syncthreads();
  for (int s = 128; s > 0; s >>= 1){ if (tid < s){ r0[tid] += r0[tid + s]; r1[tid] += r1[tid + s]; } __syncthreads(); }
  if (tid == 0){
    out[g * 2 + 0] = r0[0] + bc[0];
    out[g * 2 + 1] = r1[0] + bc[1];
  }
  __syncthreads();
  for (int p = 0; p < 8; p++){
    int cc = ordv[p < 4 ? p : 24 + p];
    const float* src = emid + (size_t)(g * 32 + cc) * MDIM;
    float* dst = out + 16 + (size_t)(g * 8 + p) * MDIM;
    for (int j = tid; j < 512; j += 256) dst[j] = src[j];
  }
}

extern "C" void kernel_launch(void* const* d_in, const int* in_sizes, int n_in,
                              void* d_out, int out_size, void* d_ws, size_t ws_size,
                              hipStream_t stream){
  const int*   idxf = (const int*)d_in[0];
  const float* tfeat= (const float*)d_in[1];
  const float* W1   = (const float*)d_in[2];
  const float* b1   = (const float*)d_in[3];
  const float* Wa1  = (const float*)d_in[4];
  const float* ba1  = (const float*)d_in[5];
  const float* Wa2  = (const float*)d_in[6];
  const float* ba2  = (const float*)d_in[7];
  const float* Wc   = (const float*)d_in[8];
  const float* bc   = (const float*)d_in[9];
  float* out = (float*)d_out;
  (void)in_sizes; (void)n_in; (void)out_size; (void)ws_size;

  char* ws = (char*)d_ws;
  size_t off = 0;
  auto alloc = [&](size_t bytes){ void* p = ws + off; off += (bytes + 255) & ~(size_t)255; return p; };
  float* lv    = (float*)alloc((size_t)N_TOT * 4);
  float* tv    = (float*)alloc((size_t)N_TOT * 4);   // reused as w inside kselect
  float* maxlw = (float*)alloc(NUM_GROUP * 4);
  float* Zw    = (float*)alloc(NUM_GROUP * 4);
  int*   cand  = (int*)alloc(NUM_GROUP * 32 * 4);
  float* ekey  = (float*)alloc(NUM_GROUP * 32 * 4);
  float* emid  = (float*)alloc((size_t)NUM_GROUP * 32 * MDIM * 4);
  float* bagp  = (float*)alloc((size_t)NUM_GROUP * 128 * MDIM * 4);
  unsigned short* W1b  = (unsigned short*)alloc((size_t)MDIM * IN_CHN * 2);
  unsigned short* Wa1b = (unsigned short*)alloc((size_t)ATT_D * MDIM * 2);
  unsigned short* midb = (unsigned short*)alloc((size_t)N_TOT * MDIM * 2);
  float* w = tv;  // tv fully consumed inside kselect before w is written

  kconv<<<2304, 256, 0, stream>>>(W1, Wa1, W1b, Wa1b);
  kgemm_mid<<<3128, 256, 0, stream>>>(idxf, tfeat, W1b, b1, midb);
  kattn<<<782, 256, 0, stream>>>(midb, Wa1b, ba1, Wa2, ba2, Wc, lv, tv);
  kselect<<<8, 256, 0, stream>>>(lv, tv, maxlw, Zw, cand, w);
  kexact<<<256, 256, 0, stream>>>(idxf, tfeat, W1, b1, Wa1, ba1, Wa2, ba2, Wc, cand, maxlw, emid, ekey);
  kbag<<<1024, 256, 0, stream>>>(midb, w, bagp);
  kfinal<<<8, 256, 0, stream>>>(bagp, Wc, bc, emid, ekey, cand, out);
}

// Round 16
// 647.006 us; speedup vs baseline: 1.0903x; 1.0903x over previous
//
#include <hip/hip_runtime.h>
#include <stdint.h>

#define N_TOT 100000
#define IN_CHN 1024
#define MDIM 512
#define ATT_D 128
#define NUM_GROUP 8
#define GROUP_SIZE 12500
#define SEGR 98  // rows per kbag segment

typedef __bf16 bf16x8 __attribute__((ext_vector_type(8)));
typedef float f32x4 __attribute__((ext_vector_type(4)));
typedef unsigned short u16x8 __attribute__((ext_vector_type(8)));

__device__ __forceinline__ unsigned short f2bf(float x){
  union { float f; unsigned u; } v; v.f = x;
  unsigned r = v.u + 0x7fffu + ((v.u >> 16) & 1u);
  return (unsigned short)(r >> 16);
}
__device__ __forceinline__ float bf2f(unsigned short h){
  union { unsigned u; float f; } v; v.u = ((unsigned)h) << 16; return v.f;
}
__device__ __forceinline__ void gload16(const void* g, void* l){
  __builtin_amdgcn_global_load_lds(
      (const __attribute__((address_space(1))) unsigned int*)g,
      (__attribute__((address_space(3))) unsigned int*)l, 16, 0, 0);
}

// ---------------- weight conversion f32 -> bf16 ----------------
__global__ __launch_bounds__(256) void kconv(const float* __restrict__ W1,
                                             const float* __restrict__ Wa1,
                                             unsigned short* __restrict__ W1b,
                                             unsigned short* __restrict__ Wa1b){
  int i = blockIdx.x * 256 + threadIdx.x;
  if (i < MDIM * IN_CHN) W1b[i] = f2bf(W1[i]);
  else {
    int j = i - MDIM * IN_CHN;
    if (j < ATT_D * MDIM) Wa1b[j] = f2bf(Wa1[j]);
  }
}

// ---------------- main gather+GEMM: mid = relu(tfeat[idx] @ W1b^T + b1) ----------------
// 128x256 tile, BK=32, 512 threads (8 waves, 2Mx4N), single-buffer 2-barrier.
// A: f32 gathered per-lane gload_lds, 128B rows, c^=row&7 (round-13-proven).
// B: bf16 64B rows, c^=(row>>1)&3 (round-11-proven). 33KB LDS -> 4 blocks/CU.
// BN=256 halves the per-instance gather count (2 bn-tiles instead of 4).
__global__ __launch_bounds__(512) void kgemm_mid(const int* __restrict__ idxf,
                                                 const float* __restrict__ tfeat,
                                                 const unsigned short* __restrict__ W1b,
                                                 const float* __restrict__ b1,
                                                 unsigned short* __restrict__ midb){
  __shared__ alignas(16) float Af[128 * 32];            // 16 KB
  __shared__ alignas(16) unsigned short Bs[256 * 32];   // 16 KB
  __shared__ int gsm[128];
  int tid = threadIdx.x;
  // bijective XCD-chunked mapping for nwg=1564 (q=195, r=4; m204 formula)
  int xcd = blockIdx.x & 7, idx = blockIdx.x >> 3;
  int tile = (xcd < 4 ? xcd * 196 : 4 * 196 + (xcd - 4) * 195) + idx;
  int bn = tile & 1, bm = tile >> 1;
  int m0 = bm * 128, n0 = bn * 256;
  if (tid < 128){ int r = m0 + tid; gsm[tid] = idxf[r < N_TOT ? r : 0]; }
  __syncthreads();

  int w = tid >> 6, l = tid & 63;          // 8 waves
  int l16 = tid & 15, hi = (tid >> 4) & 3;
  int wm = w >> 2, wn = w & 3;             // 2 x 4 wave grid

  // A staging: 2 rounds; round q covers rows q*64 + w*8 + (l>>3); chunk (l&7)^(l>>3).
  const float* asrc[2]; int adst[2];
  #pragma unroll
  for (int q = 0; q < 2; q++){
    int rowl = q * 64 + w * 8 + (l >> 3);
    asrc[q] = tfeat + (size_t)gsm[rowl] * IN_CHN + (((l & 7) ^ (l >> 3)) << 2);
    adst[q] = (q * 64 + w * 8) * 32;
  }
  // B staging: 2 rounds; round q covers rows q*128 + w*16 + (l>>2); chunk (l&3)^((l>>3)&3).
  const unsigned short* bsrc[2]; int bdst[2];
  #pragma unroll
  for (int q = 0; q < 2; q++){
    int rowl = q * 128 + w * 16 + (l >> 2);
    bsrc[q] = W1b + (size_t)(n0 + rowl) * IN_CHN + (((l & 3) ^ ((l >> 3) & 3)) << 3);
    bdst[q] = (q * 128 + w * 16) * 32;
  }

  f32x4 acc[4][4];
  #pragma unroll
  for (int a = 0; a < 4; a++)
    #pragma unroll
    for (int b = 0; b < 4; b++) acc[a][b] = (f32x4){0.f, 0.f, 0.f, 0.f};

  int r7 = l16 & 7;
  int b3 = (l16 >> 1) & 3;

  for (int s = 0; s < 32; s++){
    __syncthreads();                 // previous compute done reading LDS
    #pragma unroll
    for (int q = 0; q < 2; q++){
      gload16(asrc[q] + s * 32, &Af[adst[q]]);
      gload16(bsrc[q] + s * 32, &Bs[bdst[q]]);
    }
    __syncthreads();                 // drains DMA (implicit vmcnt(0))

    bf16x8 af[4], bfr[4];
    #pragma unroll
    for (int a = 0; a < 4; a++){
      int row = wm * 64 + a * 16 + l16;
      f32x4 lo  = *(const f32x4*)&Af[row * 32 + (((2 * hi) ^ r7) << 2)];
      f32x4 hi4 = *(const f32x4*)&Af[row * 32 + (((2 * hi + 1) ^ r7) << 2)];
      bf16x8 pk;
      pk[0] = (__bf16)lo[0]; pk[1] = (__bf16)lo[1]; pk[2] = (__bf16)lo[2]; pk[3] = (__bf16)lo[3];
      pk[4] = (__bf16)hi4[0]; pk[5] = (__bf16)hi4[1]; pk[6] = (__bf16)hi4[2]; pk[7] = (__bf16)hi4[3];
      af[a] = pk;
    }
    #pragma unroll
    for (int b = 0; b < 4; b++){
      int row = wn * 64 + b * 16 + l16;
      bfr[b] = *(const bf16x8*)&Bs[row * 32 + ((hi ^ b3) << 3)];
    }
    #pragma unroll
    for (int a = 0; a < 4; a++)
      #pragma unroll
      for (int b = 0; b < 4; b++)
        acc[a][b] = __builtin_amdgcn_mfma_f32_16x16x32_bf16(af[a], bfr[b], acc[a][b], 0, 0, 0);
  }

  #pragma unroll
  for (int b = 0; b < 4; b++){
    int col = n0 + wn * 64 + b * 16 + l16;
    float bias = b1[col];
    #pragma unroll
    for (int a = 0; a < 4; a++){
      int rbase = m0 + wm * 64 + a * 16 + hi * 4;
      #pragma unroll
      for (int q = 0; q < 4; q++){
        int row = rbase + q;
        if (row < N_TOT){
          float v = acc[a][b][q] + bias;
          midb[(size_t)row * MDIM + col] = f2bf(fmaxf(v, 0.f));
        }
      }
    }
  }
}

// ---------------- attention MLP + fused tv: gload_lds staging, proven swizzle ----------------
__global__ __launch_bounds__(256) void kattn(const unsigned short* __restrict__ midb,
                                             const unsigned short* __restrict__ Wa1b,
                                             const float* __restrict__ ba1,
                                             const float* __restrict__ Wa2,
                                             const float* __restrict__ ba2,
                                             const float* __restrict__ Wc,
                                             float* __restrict__ lv,
                                             float* __restrict__ tv){
  __shared__ alignas(16) unsigned short Asm[128 * 64];
  __shared__ alignas(16) unsigned short Bsm[128 * 64];
  __shared__ float dsh[512];
  __shared__ float part[128][2];
  int tid = threadIdx.x;
  int m0 = blockIdx.x * 128;
  for (int i = tid; i < 512; i += 256) dsh[i] = Wc[512 + i] - Wc[i];

  int w = tid >> 6, l = tid & 63;
  int l16 = tid & 15, hi = (tid >> 4) & 3;
  int wm = tid >> 7, wn = (tid >> 6) & 1;
  int scw = (l & 7) ^ (l >> 3);

  const unsigned short *asrc[4], *bsrc[4];
  int dsto[4];
  #pragma unroll
  for (int q = 0; q < 4; q++){
    int rowl = q * 32 + w * 8 + (l >> 3);
    asrc[q] = midb + (size_t)(m0 + rowl) * MDIM + scw * 8;
    bsrc[q] = Wa1b + (size_t)rowl * MDIM + scw * 8;
    dsto[q] = (q * 32 + w * 8) * 64;
  }

  f32x4 acc[4][4];
  #pragma unroll
  for (int a = 0; a < 4; a++)
    #pragma unroll
    for (int b = 0; b < 4; b++) acc[a][b] = (f32x4){0.f, 0.f, 0.f, 0.f};
  int r7 = l16 & 7;

  int rt = tid >> 1, kh = tid & 1;
  int rt7 = rt & 7;
  float t = 0.f;

  for (int s = 0; s < 8; s++){
    __syncthreads();
    #pragma unroll
    for (int q = 0; q < 4; q++){
      gload16(asrc[q] + s * 64, &Asm[dsto[q]]);
      gload16(bsrc[q] + s * 64, &Bsm[dsto[q]]);
    }
    __syncthreads();
    #pragma unroll
    for (int ks = 0; ks < 2; ks++){
      bf16x8 af[4], bfr[4];
      #pragma unroll
      for (int a = 0; a < 4; a++){
        int row = wm * 64 + a * 16 + l16;
        af[a] = *(const bf16x8*)&Asm[row * 64 + (((ks * 4 + hi) ^ r7) << 3)];
      }
      #pragma unroll
      for (int b = 0; b < 4; b++){
        int row = wn * 64 + b * 16 + l16;
        bfr[b] = *(const bf16x8*)&Bsm[row * 64 + (((ks * 4 + hi) ^ r7) << 3)];
      }
      #pragma unroll
      for (int a = 0; a < 4; a++)
        #pragma unroll
        for (int b = 0; b < 4; b++)
          acc[a][b] = __builtin_amdgcn_mfma_f32_16x16x32_bf16(af[a], bfr[b], acc[a][b], 0, 0, 0);
    }
    #pragma unroll
    for (int j = 0; j < 4; j++){
      int gc = kh * 4 + j;
      u16x8 v = *(const u16x8*)&Asm[rt * 64 + ((gc ^ rt7) << 3)];
      int kb = s * 64 + gc * 8;
      #pragma unroll
      for (int e = 0; e < 8; e++) t += bf2f((unsigned short)v[e]) * dsh[kb + e];
    }
  }
  t += __shfl_xor(t, 1);
  if (kh == 0){
    int row = m0 + rt;
    if (row < N_TOT) tv[row] = t;
  }
  #pragma unroll
  for (int a = 0; a < 4; a++){
    #pragma unroll
    for (int q = 0; q < 4; q++){
      float v = 0.f;
      #pragma unroll
      for (int b = 0; b < 4; b++){
        int col = wn * 64 + b * 16 + l16;
        v += tanhf(acc[a][b][q] + ba1[col]) * Wa2[col];
      }
      #pragma unroll
      for (int off = 1; off < 16; off <<= 1) v += __shfl_xor(v, off);
      if (l16 == 0) part[wm * 64 + a * 16 + hi * 4 + q][wn] = v;
    }
  }
  __syncthreads();
  if (tid < 128){
    int row = m0 + tid;
    if (row < N_TOT) lv[row] = part[tid][0] + part[tid][1] + ba2[0];
  }
}

// ---------------- per-group stats + top/bottom-16 + fused softmax weights ----------------
__global__ __launch_bounds__(256) void kselect(const float* __restrict__ lv,
                                               const float* __restrict__ tv,
                                               float* __restrict__ maxlw, float* __restrict__ Zw,
                                               int* __restrict__ cand,
                                               float* __restrict__ w){
  __shared__ float keys[GROUP_SIZE];
  __shared__ float candk[4096];
  __shared__ int   candi[4096];
  __shared__ float rk[256];
  __shared__ int ri[256];
  __shared__ int rs[256];
  __shared__ float sbc;
  int g = blockIdx.x, tid = threadIdx.x;
  const float* lg = lv + (size_t)g * GROUP_SIZE;
  const float* tg = tv + (size_t)g * GROUP_SIZE;

  float mx = -1e30f;
  for (int i = tid; i < GROUP_SIZE; i += 256) mx = fmaxf(mx, lg[i]);
  rk[tid] = mx; __syncthreads();
  for (int s = 128; s > 0; s >>= 1){ if (tid < s) rk[tid] = fmaxf(rk[tid], rk[tid + s]); __syncthreads(); }
  if (tid == 0) sbc = rk[0];
  __syncthreads();
  float maxl = sbc;

  float z = 0.f;
  for (int i = tid; i < GROUP_SIZE; i += 256){
    float ez = expf(lg[i] - maxl);
    z += ez;
    keys[i] = ez * tg[i];
  }
  rk[tid] = z; __syncthreads();
  for (int s = 128; s > 0; s >>= 1){ if (tid < s) rk[tid] += rk[tid + s]; __syncthreads(); }
  if (tid == 0){ maxlw[g] = maxl; Zw[g] = rk[0]; }
  __syncthreads();
  float invZ = 1.0f / rk[0];
  for (int i = tid; i < GROUP_SIZE; i += 256)
    w[(size_t)g * GROUP_SIZE + i] = expf(lg[i] - maxl) * invZ;
  __syncthreads();

  // ---- TOP-16 ----
  {
    float tk[16]; int tix[16];
    #pragma unroll
    for (int j = 0; j < 16; j++){ tk[j] = -1e30f; tix[j] = 0x7fffffff; }
    for (int i = tid; i < GROUP_SIZE; i += 256){
      float ck = keys[i];
      if (ck > tk[15]){
        int ci = i;
        #pragma unroll
        for (int j = 0; j < 16; j++){
          bool ins = ck > tk[j];
          float nk = ins ? ck : tk[j]; int ni = ins ? ci : tix[j];
          float ok = ins ? tk[j] : ck; int oi = ins ? tix[j] : ci;
          tk[j] = nk; tix[j] = ni; ck = ok; ci = oi;
        }
      }
    }
    #pragma unroll
    for (int j = 0; j < 16; j++){ candk[tid * 16 + j] = tk[j]; candi[tid * 16 + j] = tix[j]; }
  }
  __syncthreads();
  for (int it = 0; it < 16; it++){
    float bk = -1e30f; int bi = 0x7fffffff; int bs = -1;
    for (int jj = tid; jj < 4096; jj += 256){
      float k = candk[jj]; int ix = candi[jj];
      if (k > bk || (k == bk && ix < bi)){ bk = k; bi = ix; bs = jj; }
    }
    rk[tid] = bk; ri[tid] = bi; rs[tid] = bs; __syncthreads();
    for (int s = 128; s > 0; s >>= 1){
      if (tid < s){
        if (rk[tid + s] > rk[tid] || (rk[tid + s] == rk[tid] && ri[tid + s] < ri[tid])){
          rk[tid] = rk[tid + s]; ri[tid] = ri[tid + s]; rs[tid] = rs[tid + s];
        }
      }
      __syncthreads();
    }
    if (tid == 0){ cand[g * 32 + it] = ri[0]; candk[rs[0]] = -1e30f; }
    __syncthreads();
  }

  // ---- BOTTOM-16 ----
  {
    float tk[16]; int tix[16];
    #pragma unroll
    for (int j = 0; j < 16; j++){ tk[j] = 1e30f; tix[j] = -1; }
    for (int i = tid; i < GROUP_SIZE; i += 256){
      float ck = keys[i];
      if (ck <= tk[15]){
        int ci = i;
        #pragma unroll
        for (int j = 0; j < 16; j++){
          bool ins = ck <= tk[j];   // ties: later (larger) idx goes first
          float nk = ins ? ck : tk[j]; int ni = ins ? ci : tix[j];
          float ok = ins ? tk[j] : ck; int oi = ins ? tix[j] : ci;
          tk[j] = nk; tix[j] = ni; ck = ok; ci = oi;
        }
      }
    }
    #pragma unroll
    for (int j = 0; j < 16; j++){ candk[tid * 16 + j] = tk[j]; candi[tid * 16 + j] = tix[j]; }
  }
  __syncthreads();
  for (int it = 0; it < 16; it++){
    float bk = 1e30f; int bi = -1; int bs = -1;
    for (int jj = tid; jj < 4096; jj += 256){
      float k = candk[jj]; int ix = candi[jj];
      if (k < bk || (k == bk && ix > bi)){ bk = k; bi = ix; bs = jj; }
    }
    rk[tid] = bk; ri[tid] = bi; rs[tid] = bs; __syncthreads();
    for (int s = 128; s > 0; s >>= 1){
      if (tid < s){
        if (rk[tid + s] < rk[tid] || (rk[tid + s] == rk[tid] && ri[tid + s] > ri[tid])){
          rk[tid] = rk[tid + s]; ri[tid] = ri[tid + s]; rs[tid] = rs[tid + s];
        }
      }
      __syncthreads();
    }
    if (tid == 0){ cand[g * 32 + 16 + it] = ri[0]; candk[rs[0]] = 1e30f; }
    __syncthreads();
  }
}

// ---------------- exact f32 recompute of 256 candidate rows ----------------
__global__ __launch_bounds__(256) void kexact(const int* __restrict__ idxf,
                                              const float* __restrict__ tfeat,
                                              const float* __restrict__ W1,
                                              const float* __restrict__ b1,
                                              const float* __restrict__ Wa1,
                                              const float* __restrict__ ba1,
                                              const float* __restrict__ Wa2,
                                              const float* __restrict__ ba2,
                                              const float* __restrict__ Wc,
                                              const int* __restrict__ cand,
                                              const float* __restrict__ maxlw,
                                              float* __restrict__ emid, float* __restrict__ ekey){
  __shared__ float subs[1024];
  __shared__ float midc[512];
  __shared__ float hs[128];
  __shared__ float red[256];
  __shared__ float tsh;
  int bid = blockIdx.x; int g = bid >> 5, c = bid & 31; int tid = threadIdx.x;
  int s = cand[g * 32 + c];
  int inst = idxf[g * GROUP_SIZE + s];
  ((float4*)subs)[tid] = ((const float4*)(tfeat + (size_t)inst * IN_CHN))[tid];
  __syncthreads();

  float a0 = b1[tid], a1 = b1[tid + 256];
  const float4* w0 = (const float4*)(W1 + (size_t)tid * IN_CHN);
  const float4* w1 = (const float4*)(W1 + ((size_t)tid + 256) * IN_CHN);
  const float4* s4 = (const float4*)subs;
  #pragma unroll 4
  for (int k = 0; k < 256; k++){
    float4 sv = s4[k], wva = w0[k], wvb = w1[k];
    a0 += sv.x * wva.x + sv.y * wva.y + sv.z * wva.z + sv.w * wva.w;
    a1 += sv.x * wvb.x + sv.y * wvb.y + sv.z * wvb.z + sv.w * wvb.w;
  }
  a0 = fmaxf(a0, 0.f); a1 = fmaxf(a1, 0.f);
  midc[tid] = a0; midc[tid + 256] = a1;
  size_t eo = (size_t)(g * 32 + c) * MDIM;
  emid[eo + tid] = a0; emid[eo + tid + 256] = a1;
  __syncthreads();

  if (tid < 128){
    const float4* wr = (const float4*)(Wa1 + (size_t)tid * MDIM);
    const float4* m4 = (const float4*)midc;
    float h = ba1[tid];
    #pragma unroll 4
    for (int j = 0; j < 128; j++){
      float4 mv = m4[j], wv = wr[j];
      h += mv.x * wv.x + mv.y * wv.y + mv.z * wv.z + mv.w * wv.w;
    }
    hs[tid] = tanhf(h) * Wa2[tid];
  }
  __syncthreads();

  float tp = midc[tid] * (Wc[512 + tid] - Wc[tid]) + midc[tid + 256] * (Wc[768 + tid] - Wc[256 + tid]);
  red[tid] = tp; __syncthreads();
  for (int st = 128; st > 0; st >>= 1){ if (tid < st) red[tid] += red[tid + st]; __syncthreads(); }
  if (tid == 0) tsh = red[0];
  __syncthreads();
  red[tid] = (tid < 128) ? hs[tid] : 0.f; __syncthreads();
  for (int st = 128; st > 0; st >>= 1){ if (tid < st) red[tid] += red[tid + st]; __syncthreads(); }
  if (tid == 0){
    float lval = red[0] + ba2[0];
    ekey[g * 32 + c] = expf(lval - maxlw[g]) * tsh;
  }
}

// ---------------- weighted bag-sum: 128 segments x 8 groups, partials ----------------
__global__ __launch_bounds__(256) void kbag(const unsigned short* __restrict__ midb,
                                            const float* __restrict__ w,
                                            float* __restrict__ bagp){
  __shared__ float wl[SEGR];
  int g = blockIdx.x >> 7, seg = blockIdx.x & 127, tid = threadIdx.x;
  int i0 = seg * SEGR;
  int nr = GROUP_SIZE - i0; if (nr > SEGR) nr = SEGR;
  size_t base = (size_t)g * GROUP_SIZE;
  if (tid < nr) wl[tid] = w[base + i0 + tid];
  __syncthreads();
  float a0 = 0.f, a1 = 0.f;
  const unsigned short* mp = midb + (base + i0) * MDIM + 2 * tid;
  int i = 0;
  for (; i + 2 <= nr; i += 2){
    unsigned pk0 = *(const unsigned*)(mp + (size_t)i * MDIM);
    unsigned pk1 = *(const unsigned*)(mp + (size_t)(i + 1) * MDIM);
    float w0 = wl[i], w1 = wl[i + 1];
    a0 += w0 * bf2f((unsigned short)(pk0 & 0xffff)) + w1 * bf2f((unsigned short)(pk1 & 0xffff));
    a1 += w0 * bf2f((unsigned short)(pk0 >> 16)) + w1 * bf2f((unsigned short)(pk1 >> 16));
  }
  if (i < nr){
    unsigned pk0 = *(const unsigned*)(mp + (size_t)i * MDIM);
    float w0 = wl[i];
    a0 += w0 * bf2f((unsigned short)(pk0 & 0xffff));
    a1 += w0 * bf2f((unsigned short)(pk0 >> 16));
  }
  float* dst = bagp + (size_t)blockIdx.x * MDIM + 2 * tid;
  dst[0] = a0; dst[1] = a1;
}

// ---------------- final: exact re-rank, preds, feature copy — FLOAT32 output ----------------
__global__ __launch_bounds__(256) void kfinal(const float* __restrict__ bagp,
                                              const float* __restrict__ Wc,
                                              const float* __restrict__ bc,
                                              const float* __restrict__ emid,
                                              const float* __restrict__ ekey,
                                              const int* __restrict__ cand,
                                              float* __restrict__ out){
  __shared__ float k32[32];
  __shared__ int s32[32];
  __shared__ int ordv[32];
  __shared__ float r0[256], r1[256];
  int g = blockIdx.x, tid = threadIdx.x;
  if (tid < 32){ k32[tid] = ekey[g * 32 + tid]; s32[tid] = cand[g * 32 + tid]; }
  __syncthreads();
  if (tid == 0){
    unsigned used = 0;
    for (int a = 0; a < 32; a++){
      int best = -1;
      for (int b = 0; b < 32; b++){
        if ((used >> b) & 1u) continue;
        if (best < 0 || k32[b] > k32[best] || (k32[b] == k32[best] && s32[b] < s32[best])) best = b;
      }
      used |= 1u << best;
      ordv[a] = best;
    }
  }
  float p0 = 0.f, p1 = 0.f;
  for (int j = tid; j < 512; j += 256){
    float bv = 0.f;
    for (int s2 = 0; s2 < 128; s2++) bv += bagp[(size_t)(g * 128 + s2) * MDIM + j];
    p0 += bv * Wc[j];
    p1 += bv * Wc[512 + j];
  }
  r0[tid] = p0; r1[tid] = p1; __syncthreads();
  for (int s = 128; s > 0; s >>= 1){ if (tid < s){ r0[tid] += r0[tid + s]; r1[tid] += r1[tid + s]; } __syncthreads(); }
  if (tid == 0){
    out[g * 2 + 0] = r0[0] + bc[0];
    out[g * 2 + 1] = r1[0] + bc[1];
  }
  __syncthreads();
  for (int p = 0; p < 8; p++){
    int cc = ordv[p < 4 ? p : 24 + p];
    const float* src = emid + (size_t)(g * 32 + cc) * MDIM;
    float* dst = out + 16 + (size_t)(g * 8 + p) * MDIM;
    for (int j = tid; j < 512; j += 256) dst[j] = src[j];
  }
}

extern "C" void kernel_launch(void* const* d_in, const int* in_sizes, int n_in,
                              void* d_out, int out_size, void* d_ws, size_t ws_size,
                              hipStream_t stream){
  const int*   idxf = (const int*)d_in[0];
  const float* tfeat= (const float*)d_in[1];
  const float* W1   = (const float*)d_in[2];
  const float* b1   = (const float*)d_in[3];
  const float* Wa1  = (const float*)d_in[4];
  const float* ba1  = (const float*)d_in[5];
  const float* Wa2  = (const float*)d_in[6];
  const float* ba2  = (const float*)d_in[7];
  const float* Wc   = (const float*)d_in[8];
  const float* bc   = (const float*)d_in[9];
  float* out = (float*)d_out;
  (void)in_sizes; (void)n_in; (void)out_size; (void)ws_size;

  char* ws = (char*)d_ws;
  size_t off = 0;
  auto alloc = [&](size_t bytes){ void* p = ws + off; off += (bytes + 255) & ~(size_t)255; return p; };
  float* lv    = (float*)alloc((size_t)N_TOT * 4);
  float* tv    = (float*)alloc((size_t)N_TOT * 4);   // reused as w inside kselect
  float* maxlw = (float*)alloc(NUM_GROUP * 4);
  float* Zw    = (float*)alloc(NUM_GROUP * 4);
  int*   cand  = (int*)alloc(NUM_GROUP * 32 * 4);
  float* ekey  = (float*)alloc(NUM_GROUP * 32 * 4);
  float* emid  = (float*)alloc((size_t)NUM_GROUP * 32 * MDIM * 4);
  float* bagp  = (float*)alloc((size_t)NUM_GROUP * 128 * MDIM * 4);
  unsigned short* W1b  = (unsigned short*)alloc((size_t)MDIM * IN_CHN * 2);
  unsigned short* Wa1b = (unsigned short*)alloc((size_t)ATT_D * MDIM * 2);
  unsigned short* midb = (unsigned short*)alloc((size_t)N_TOT * MDIM * 2);
  float* w = tv;  // tv fully consumed inside kselect before w is written

  kconv<<<2304, 256, 0, stream>>>(W1, Wa1, W1b, Wa1b);
  kgemm_mid<<<1564, 512, 0, stream>>>(idxf, tfeat, W1b, b1, midb);
  kattn<<<782, 256, 0, stream>>>(midb, Wa1b, ba1, Wa2, ba2, Wc, lv, tv);
  kselect<<<8, 256, 0, stream>>>(lv, tv, maxlw, Zw, cand, w);
  kexact<<<256, 256, 0, stream>>>(idxf, tfeat, W1, b1, Wa1, ba1, Wa2, ba2, Wc, cand, maxlw, emid, ekey);
  kbag<<<1024, 256, 0, stream>>>(midb, w, bagp);
  kfinal<<<8, 256, 0, stream>>>(bagp, Wc, bc, emid, ekey, cand, out);
}

// Round 17
// 622.505 us; speedup vs baseline: 1.1332x; 1.0394x over previous
//
#include <hip/hip_runtime.h>
#include <stdint.h>

#define N_TOT 100000
#define IN_CHN 1024
#define MDIM 512
#define ATT_D 128
#define NUM_GROUP 8
#define GROUP_SIZE 12500
#define SEGB 196  // rows per kbag segment (64 segs/group)

typedef __bf16 bf16x8 __attribute__((ext_vector_type(8)));
typedef float f32x4 __attribute__((ext_vector_type(4)));
typedef unsigned short u16x8 __attribute__((ext_vector_type(8)));

__device__ __forceinline__ unsigned short f2bf(float x){
  union { float f; unsigned u; } v; v.f = x;
  unsigned r = v.u + 0x7fffu + ((v.u >> 16) & 1u);
  return (unsigned short)(r >> 16);
}
__device__ __forceinline__ float bf2f(unsigned short h){
  union { unsigned u; float f; } v; v.u = ((unsigned)h) << 16; return v.f;
}
__device__ __forceinline__ void gload16(const void* g, void* l){
  __builtin_amdgcn_global_load_lds(
      (const __attribute__((address_space(1))) unsigned int*)g,
      (__attribute__((address_space(3))) unsigned int*)l, 16, 0, 0);
}

// ---------------- weight conversion f32 -> bf16 ----------------
__global__ __launch_bounds__(256) void kconv(const float* __restrict__ W1,
                                             const float* __restrict__ Wa1,
                                             unsigned short* __restrict__ W1b,
                                             unsigned short* __restrict__ Wa1b){
  int i = blockIdx.x * 256 + threadIdx.x;
  if (i < MDIM * IN_CHN) W1b[i] = f2bf(W1[i]);
  else {
    int j = i - MDIM * IN_CHN;
    if (j < ATT_D * MDIM) Wa1b[j] = f2bf(Wa1[j]);
  }
}

// ---------------- main gather+GEMM + fused tv-partials ----------------
// mid = relu(tfeat[idx] @ W1b^T + b1); tvp[bn][row] = sum_{cols in bn} mid*d
// 128x256 tile, BK=32, 512 threads (8 waves 2Mx4N), single-buffer 2-barrier.
__global__ __launch_bounds__(512) void kgemm_mid(const int* __restrict__ idxf,
                                                 const float* __restrict__ tfeat,
                                                 const unsigned short* __restrict__ W1b,
                                                 const float* __restrict__ b1,
                                                 const float* __restrict__ Wc,
                                                 unsigned short* __restrict__ midb,
                                                 float* __restrict__ tvp){
  __shared__ alignas(16) float Af[128 * 32];            // 16 KB
  __shared__ alignas(16) unsigned short Bs[256 * 32];   // 16 KB
  __shared__ int gsm[128];
  __shared__ float dcol[256];
  __shared__ float tvacc[128][4];
  int tid = threadIdx.x;
  // bijective XCD-chunked mapping for nwg=1564 (q=195, r=4)
  int xcd = blockIdx.x & 7, idx = blockIdx.x >> 3;
  int tile = (xcd < 4 ? xcd * 196 : 4 * 196 + (xcd - 4) * 195) + idx;
  int bn = tile & 1, bm = tile >> 1;
  int m0 = bm * 128, n0 = bn * 256;
  if (tid < 128){ int r = m0 + tid; gsm[tid] = idxf[r < N_TOT ? r : 0]; }
  if (tid >= 128 && tid < 384){
    int c = tid - 128;
    dcol[c] = Wc[512 + n0 + c] - Wc[n0 + c];
  }
  __syncthreads();

  int w = tid >> 6, l = tid & 63;          // 8 waves
  int l16 = tid & 15, hi = (tid >> 4) & 3;
  int wm = w >> 2, wn = w & 3;             // 2 x 4 wave grid

  const float* asrc[2]; int adst[2];
  #pragma unroll
  for (int q = 0; q < 2; q++){
    int rowl = q * 64 + w * 8 + (l >> 3);
    asrc[q] = tfeat + (size_t)gsm[rowl] * IN_CHN + (((l & 7) ^ (l >> 3)) << 2);
    adst[q] = (q * 64 + w * 8) * 32;
  }
  const unsigned short* bsrc[2]; int bdst[2];
  #pragma unroll
  for (int q = 0; q < 2; q++){
    int rowl = q * 128 + w * 16 + (l >> 2);
    bsrc[q] = W1b + (size_t)(n0 + rowl) * IN_CHN + (((l & 3) ^ ((l >> 3) & 3)) << 3);
    bdst[q] = (q * 128 + w * 16) * 32;
  }

  f32x4 acc[4][4];
  #pragma unroll
  for (int a = 0; a < 4; a++)
    #pragma unroll
    for (int b = 0; b < 4; b++) acc[a][b] = (f32x4){0.f, 0.f, 0.f, 0.f};

  int r7 = l16 & 7;
  int b3 = (l16 >> 1) & 3;

  for (int s = 0; s < 32; s++){
    __syncthreads();
    #pragma unroll
    for (int q = 0; q < 2; q++){
      gload16(asrc[q] + s * 32, &Af[adst[q]]);
      gload16(bsrc[q] + s * 32, &Bs[bdst[q]]);
    }
    __syncthreads();

    bf16x8 af[4], bfr[4];
    #pragma unroll
    for (int a = 0; a < 4; a++){
      int row = wm * 64 + a * 16 + l16;
      f32x4 lo  = *(const f32x4*)&Af[row * 32 + (((2 * hi) ^ r7) << 2)];
      f32x4 hi4 = *(const f32x4*)&Af[row * 32 + (((2 * hi + 1) ^ r7) << 2)];
      bf16x8 pk;
      pk[0] = (__bf16)lo[0]; pk[1] = (__bf16)lo[1]; pk[2] = (__bf16)lo[2]; pk[3] = (__bf16)lo[3];
      pk[4] = (__bf16)hi4[0]; pk[5] = (__bf16)hi4[1]; pk[6] = (__bf16)hi4[2]; pk[7] = (__bf16)hi4[3];
      af[a] = pk;
    }
    #pragma unroll
    for (int b = 0; b < 4; b++){
      int row = wn * 64 + b * 16 + l16;
      bfr[b] = *(const bf16x8*)&Bs[row * 32 + ((hi ^ b3) << 3)];
    }
    #pragma unroll
    for (int a = 0; a < 4; a++)
      #pragma unroll
      for (int b = 0; b < 4; b++)
        acc[a][b] = __builtin_amdgcn_mfma_f32_16x16x32_bf16(af[a], bfr[b], acc[a][b], 0, 0, 0);
  }

  // epilogue: relu+bias, store midb, accumulate tv partial over this block's 256 cols
  float biasv[4];
  #pragma unroll
  for (int b = 0; b < 4; b++) biasv[b] = b1[n0 + wn * 64 + b * 16 + l16];
  #pragma unroll
  for (int a = 0; a < 4; a++){
    #pragma unroll
    for (int q = 0; q < 4; q++){
      int row = m0 + wm * 64 + a * 16 + hi * 4 + q;
      float t = 0.f;
      #pragma unroll
      for (int b = 0; b < 4; b++){
        int colL = wn * 64 + b * 16 + l16;
        float v = fmaxf(acc[a][b][q] + biasv[b], 0.f);
        t += v * dcol[colL];
        if (row < N_TOT) midb[(size_t)row * MDIM + n0 + colL] = f2bf(v);
      }
      t += __shfl_xor(t, 1); t += __shfl_xor(t, 2);
      t += __shfl_xor(t, 4); t += __shfl_xor(t, 8);
      if (l16 == 0) tvacc[wm * 64 + a * 16 + hi * 4 + q][wn] = t;
    }
  }
  __syncthreads();
  if (tid < 128){
    int row = m0 + tid;
    if (row < N_TOT)
      tvp[(size_t)bn * N_TOT + row] = tvacc[tid][0] + tvacc[tid][1] + tvacc[tid][2] + tvacc[tid][3];
  }
}

// ---------------- attention MLP (lv only): gload_lds staging, proven swizzle ----------------
__global__ __launch_bounds__(256) void kattn(const unsigned short* __restrict__ midb,
                                             const unsigned short* __restrict__ Wa1b,
                                             const float* __restrict__ ba1,
                                             const float* __restrict__ Wa2,
                                             const float* __restrict__ ba2,
                                             float* __restrict__ lv){
  __shared__ alignas(16) unsigned short Asm[128 * 64];
  __shared__ alignas(16) unsigned short Bsm[128 * 64];
  __shared__ float part[128][2];
  int tid = threadIdx.x;
  int m0 = blockIdx.x * 128;

  int w = tid >> 6, l = tid & 63;
  int l16 = tid & 15, hi = (tid >> 4) & 3;
  int wm = tid >> 7, wn = (tid >> 6) & 1;
  int scw = (l & 7) ^ (l >> 3);

  const unsigned short *asrc[4], *bsrc[4];
  int dsto[4];
  #pragma unroll
  for (int q = 0; q < 4; q++){
    int rowl = q * 32 + w * 8 + (l >> 3);
    asrc[q] = midb + (size_t)(m0 + rowl) * MDIM + scw * 8;
    bsrc[q] = Wa1b + (size_t)rowl * MDIM + scw * 8;
    dsto[q] = (q * 32 + w * 8) * 64;
  }

  f32x4 acc[4][4];
  #pragma unroll
  for (int a = 0; a < 4; a++)
    #pragma unroll
    for (int b = 0; b < 4; b++) acc[a][b] = (f32x4){0.f, 0.f, 0.f, 0.f};
  int r7 = l16 & 7;

  for (int s = 0; s < 8; s++){
    __syncthreads();
    #pragma unroll
    for (int q = 0; q < 4; q++){
      gload16(asrc[q] + s * 64, &Asm[dsto[q]]);
      gload16(bsrc[q] + s * 64, &Bsm[dsto[q]]);
    }
    __syncthreads();
    #pragma unroll
    for (int ks = 0; ks < 2; ks++){
      bf16x8 af[4], bfr[4];
      #pragma unroll
      for (int a = 0; a < 4; a++){
        int row = wm * 64 + a * 16 + l16;
        af[a] = *(const bf16x8*)&Asm[row * 64 + (((ks * 4 + hi) ^ r7) << 3)];
      }
      #pragma unroll
      for (int b = 0; b < 4; b++){
        int row = wn * 64 + b * 16 + l16;
        bfr[b] = *(const bf16x8*)&Bsm[row * 64 + (((ks * 4 + hi) ^ r7) << 3)];
      }
      #pragma unroll
      for (int a = 0; a < 4; a++)
        #pragma unroll
        for (int b = 0; b < 4; b++)
          acc[a][b] = __builtin_amdgcn_mfma_f32_16x16x32_bf16(af[a], bfr[b], acc[a][b], 0, 0, 0);
    }
  }
  #pragma unroll
  for (int a = 0; a < 4; a++){
    #pragma unroll
    for (int q = 0; q < 4; q++){
      float v = 0.f;
      #pragma unroll
      for (int b = 0; b < 4; b++){
        int col = wn * 64 + b * 16 + l16;
        v += tanhf(acc[a][b][q] + ba1[col]) * Wa2[col];
      }
      #pragma unroll
      for (int off = 1; off < 16; off <<= 1) v += __shfl_xor(v, off);
      if (l16 == 0) part[wm * 64 + a * 16 + hi * 4 + q][wn] = v;
    }
  }
  __syncthreads();
  if (tid < 128){
    int row = m0 + tid;
    if (row < N_TOT) lv[row] = part[tid][0] + part[tid][1] + ba2[0];
  }
}

// ---------------- per-group stats + top/bottom-16 + fused softmax weights ----------------
__global__ __launch_bounds__(256) void kselect(const float* __restrict__ lv,
                                               const float* __restrict__ tvp,
                                               float* __restrict__ maxlw, float* __restrict__ Zw,
                                               int* __restrict__ cand,
                                               float* __restrict__ w){
  __shared__ float keys[GROUP_SIZE];
  __shared__ float candk[4096];
  __shared__ int   candi[4096];
  __shared__ float rk[256];
  __shared__ int ri[256];
  __shared__ int rs[256];
  __shared__ float sbc;
  int g = blockIdx.x, tid = threadIdx.x;
  const float* lg = lv + (size_t)g * GROUP_SIZE;

  float mx = -1e30f;
  for (int i = tid; i < GROUP_SIZE; i += 256) mx = fmaxf(mx, lg[i]);
  rk[tid] = mx; __syncthreads();
  for (int s = 128; s > 0; s >>= 1){ if (tid < s) rk[tid] = fmaxf(rk[tid], rk[tid + s]); __syncthreads(); }
  if (tid == 0) sbc = rk[0];
  __syncthreads();
  float maxl = sbc;

  float z = 0.f;
  for (int i = tid; i < GROUP_SIZE; i += 256){
    float ez = expf(lg[i] - maxl);
    z += ez;
    size_t gi = (size_t)g * GROUP_SIZE + i;
    keys[i] = ez * (tvp[gi] + tvp[N_TOT + gi]);
  }
  rk[tid] = z; __syncthreads();
  for (int s = 128; s > 0; s >>= 1){ if (tid < s) rk[tid] += rk[tid + s]; __syncthreads(); }
  if (tid == 0){ maxlw[g] = maxl; Zw[g] = rk[0]; }
  __syncthreads();
  float invZ = 1.0f / rk[0];
  for (int i = tid; i < GROUP_SIZE; i += 256)
    w[(size_t)g * GROUP_SIZE + i] = expf(lg[i] - maxl) * invZ;
  __syncthreads();

  // ---- TOP-16 ----
  {
    float tk[16]; int tix[16];
    #pragma unroll
    for (int j = 0; j < 16; j++){ tk[j] = -1e30f; tix[j] = 0x7fffffff; }
    for (int i = tid; i < GROUP_SIZE; i += 256){
      float ck = keys[i];
      if (ck > tk[15]){
        int ci = i;
        #pragma unroll
        for (int j = 0; j < 16; j++){
          bool ins = ck > tk[j];
          float nk = ins ? ck : tk[j]; int ni = ins ? ci : tix[j];
          float ok = ins ? tk[j] : ck; int oi = ins ? tix[j] : ci;
          tk[j] = nk; tix[j] = ni; ck = ok; ci = oi;
        }
      }
    }
    #pragma unroll
    for (int j = 0; j < 16; j++){ candk[tid * 16 + j] = tk[j]; candi[tid * 16 + j] = tix[j]; }
  }
  __syncthreads();
  for (int it = 0; it < 16; it++){
    float bk = -1e30f; int bi = 0x7fffffff; int bs = -1;
    for (int jj = tid; jj < 4096; jj += 256){
      float k = candk[jj]; int ix = candi[jj];
      if (k > bk || (k == bk && ix < bi)){ bk = k; bi = ix; bs = jj; }
    }
    rk[tid] = bk; ri[tid] = bi; rs[tid] = bs; __syncthreads();
    for (int s = 128; s > 0; s >>= 1){
      if (tid < s){
        if (rk[tid + s] > rk[tid] || (rk[tid + s] == rk[tid] && ri[tid + s] < ri[tid])){
          rk[tid] = rk[tid + s]; ri[tid] = ri[tid + s]; rs[tid] = rs[tid + s];
        }
      }
      __syncthreads();
    }
    if (tid == 0){ cand[g * 32 + it] = ri[0]; candk[rs[0]] = -1e30f; }
    __syncthreads();
  }

  // ---- BOTTOM-16 ----
  {
    float tk[16]; int tix[16];
    #pragma unroll
    for (int j = 0; j < 16; j++){ tk[j] = 1e30f; tix[j] = -1; }
    for (int i = tid; i < GROUP_SIZE; i += 256){
      float ck = keys[i];
      if (ck <= tk[15]){
        int ci = i;
        #pragma unroll
        for (int j = 0; j < 16; j++){
          bool ins = ck <= tk[j];   // ties: later (larger) idx goes first
          float nk = ins ? ck : tk[j]; int ni = ins ? ci : tix[j];
          float ok = ins ? tk[j] : ck; int oi = ins ? tix[j] : ci;
          tk[j] = nk; tix[j] = ni; ck = ok; ci = oi;
        }
      }
    }
    #pragma unroll
    for (int j = 0; j < 16; j++){ candk[tid * 16 + j] = tk[j]; candi[tid * 16 + j] = tix[j]; }
  }
  __syncthreads();
  for (int it = 0; it < 16; it++){
    float bk = 1e30f; int bi = -1; int bs = -1;
    for (int jj = tid; jj < 4096; jj += 256){
      float k = candk[jj]; int ix = candi[jj];
      if (k < bk || (k == bk && ix > bi)){ bk = k; bi = ix; bs = jj; }
    }
    rk[tid] = bk; ri[tid] = bi; rs[tid] = bs; __syncthreads();
    for (int s = 128; s > 0; s >>= 1){
      if (tid < s){
        if (rk[tid + s] < rk[tid] || (rk[tid + s] == rk[tid] && ri[tid + s] > ri[tid])){
          rk[tid] = rk[tid + s]; ri[tid] = ri[tid + s]; rs[tid] = rs[tid + s];
        }
      }
      __syncthreads();
    }
    if (tid == 0){ cand[g * 32 + 16 + it] = ri[0]; candk[rs[0]] = 1e30f; }
    __syncthreads();
  }
}

// ---------------- exact f32 recompute of 256 candidate rows ----------------
__global__ __launch_bounds__(256) void kexact(const int* __restrict__ idxf,
                                              const float* __restrict__ tfeat,
                                              const float* __restrict__ W1,
                                              const float* __restrict__ b1,
                                              const float* __restrict__ Wa1,
                                              const float* __restrict__ ba1,
                                              const float* __restrict__ Wa2,
                                              const float* __restrict__ ba2,
                                              const float* __restrict__ Wc,
                                              const int* __restrict__ cand,
                                              const float* __restrict__ maxlw,
                                              float* __restrict__ emid, float* __restrict__ ekey){
  __shared__ float subs[1024];
  __shared__ float midc[512];
  __shared__ float hs[128];
  __shared__ float red[256];
  __shared__ float tsh;
  int bid = blockIdx.x; int g = bid >> 5, c = bid & 31; int tid = threadIdx.x;
  int s = cand[g * 32 + c];
  int inst = idxf[g * GROUP_SIZE + s];
  ((float4*)subs)[tid] = ((const float4*)(tfeat + (size_t)inst * IN_CHN))[tid];
  __syncthreads();

  float a0 = b1[tid], a1 = b1[tid + 256];
  const float4* w0 = (const float4*)(W1 + (size_t)tid * IN_CHN);
  const float4* w1 = (const float4*)(W1 + ((size_t)tid + 256) * IN_CHN);
  const float4* s4 = (const float4*)subs;
  #pragma unroll 4
  for (int k = 0; k < 256; k++){
    float4 sv = s4[k], wva = w0[k], wvb = w1[k];
    a0 += sv.x * wva.x + sv.y * wva.y + sv.z * wva.z + sv.w * wva.w;
    a1 += sv.x * wvb.x + sv.y * wvb.y + sv.z * wvb.z + sv.w * wvb.w;
  }
  a0 = fmaxf(a0, 0.f); a1 = fmaxf(a1, 0.f);
  midc[tid] = a0; midc[tid + 256] = a1;
  size_t eo = (size_t)(g * 32 + c) * MDIM;
  emid[eo + tid] = a0; emid[eo + tid + 256] = a1;
  __syncthreads();

  if (tid < 128){
    const float4* wr = (const float4*)(Wa1 + (size_t)tid * MDIM);
    const float4* m4 = (const float4*)midc;
    float h = ba1[tid];
    #pragma unroll 4
    for (int j = 0; j < 128; j++){
      float4 mv = m4[j], wv = wr[j];
      h += mv.x * wv.x + mv.y * wv.y + mv.z * wv.z + mv.w * wv.w;
    }
    hs[tid] = tanhf(h) * Wa2[tid];
  }
  __syncthreads();

  float tp = midc[tid] * (Wc[512 + tid] - Wc[tid]) + midc[tid + 256] * (Wc[768 + tid] - Wc[256 + tid]);
  red[tid] = tp; __syncthreads();
  for (int st = 128; st > 0; st >>= 1){ if (tid < st) red[tid] += red[tid + st]; __syncthreads(); }
  if (tid == 0) tsh = red[0];
  __syncthreads();
  red[tid] = (tid < 128) ? hs[tid] : 0.f; __syncthreads();
  for (int st = 128; st > 0; st >>= 1){ if (tid < st) red[tid] += red[tid + st]; __syncthreads(); }
  if (tid == 0){
    float lval = red[0] + ba2[0];
    ekey[g * 32 + c] = expf(lval - maxlw[g]) * tsh;
  }
}

// ---------------- weighted bag-sum: 64 segments x 8 groups, 16B/lane ----------------
__global__ __launch_bounds__(256) void kbag(const unsigned short* __restrict__ midb,
                                            const float* __restrict__ w,
                                            float* __restrict__ bagp){
  __shared__ float wl[SEGB];
  __shared__ float red[4][512];
  int g = blockIdx.x >> 6, seg = blockIdx.x & 63, tid = threadIdx.x;
  int rg = tid >> 6, lane = tid & 63;
  int i0 = seg * SEGB;
  int nr = GROUP_SIZE - i0; if (nr > SEGB) nr = SEGB;
  size_t base = (size_t)g * GROUP_SIZE;
  if (tid < nr) wl[tid] = w[base + i0 + tid];
  __syncthreads();
  float a[8] = {0.f,0.f,0.f,0.f,0.f,0.f,0.f,0.f};
  const unsigned short* mp = midb + (base + i0) * MDIM + lane * 8;
  for (int i = rg; i < nr; i += 4){
    float wi = wl[i];
    u16x8 v = *(const u16x8*)(mp + (size_t)i * MDIM);
    #pragma unroll
    for (int e = 0; e < 8; e++) a[e] += wi * bf2f((unsigned short)v[e]);
  }
  #pragma unroll
  for (int e = 0; e < 8; e++) red[rg][lane * 8 + e] = a[e];
  __syncthreads();
  if (rg == 0){
    float* dst = bagp + (size_t)blockIdx.x * MDIM + lane * 8;
    #pragma unroll
    for (int e = 0; e < 8; e++){
      int c = lane * 8 + e;
      dst[e] = red[0][c] + red[1][c] + red[2][c] + red[3][c];
    }
  }
}

// ---------------- final: exact re-rank, preds, feature copy — FLOAT32 output ----------------
__global__ __launch_bounds__(256) void kfinal(const float* __restrict__ bagp,
                                              const float* __restrict__ Wc,
                                              const float* __restrict__ bc,
                                              const float* __restrict__ emid,
                                              const float* __restrict__ ekey,
                                              const int* __restrict__ cand,
                                              float* __restrict__ out){
  __shared__ float k32[32];
  __shared__ int s32[32];
  __shared__ int ordv[32];
  __shared__ float r0[256], r1[256];
  int g = blockIdx.x, tid = threadIdx.x;
  if (tid < 32){ k32[tid] = ekey[g * 32 + tid]; s32[tid] = cand[g * 32 + tid]; }
  __syncthreads();
  if (tid == 0){
    unsigned used = 0;
    for (int a = 0; a < 32; a++){
      int best = -1;
      for (int b = 0; b < 32; b++){
        if ((used >> b) & 1u) continue;
        if (best < 0 || k32[b] > k32[best] || (k32[b] == k32[best] && s32[b] < s32[best])) best = b;
      }
      used |= 1u << best;
      ordv[a] = best;
    }
  }
  float p0 = 0.f, p1 = 0.f;
  for (int j = tid; j < 512; j += 256){
    float bv = 0.f;
    for (int s2 = 0; s2 < 64; s2++) bv += bagp[(size_t)(g * 64 + s2) * MDIM + j];
    p0 += bv * Wc[j];
    p1 += bv * Wc[512 + j];
  }
  r0[tid] = p0; r1[tid] = p1; __syncthreads();
  for (int s = 128; s > 0; s >>= 1){ if (tid < s){ r0[tid] += r0[tid + s]; r1[tid] += r1[tid + s]; } __syncthreads(); }
  if (tid == 0){
    out[g * 2 + 0] = r0[0] + bc[0];
    out[g * 2 + 1] = r1[0] + bc[1];
  }
  __syncthreads();
  for (int p = 0; p < 8; p++){
    int cc = ordv[p < 4 ? p : 24 + p];
    const float* src = emid + (size_t)(g * 32 + cc) * MDIM;
    float* dst = out + 16 + (size_t)(g * 8 + p) * MDIM;
    for (int j = tid; j < 512; j += 256) dst[j] = src[j];
  }
}

extern "C" void kernel_launch(void* const* d_in, const int* in_sizes, int n_in,
                              void* d_out, int out_size, void* d_ws, size_t ws_size,
                              hipStream_t stream){
  const int*   idxf = (const int*)d_in[0];
  const float* tfeat= (const float*)d_in[1];
  const float* W1   = (const float*)d_in[2];
  const float* b1   = (const float*)d_in[3];
  const float* Wa1  = (const float*)d_in[4];
  const float* ba1  = (const float*)d_in[5];
  const float* Wa2  = (const float*)d_in[6];
  const float* ba2  = (const float*)d_in[7];
  const float* Wc   = (const float*)d_in[8];
  const float* bc   = (const float*)d_in[9];
  float* out = (float*)d_out;
  (void)in_sizes; (void)n_in; (void)out_size; (void)ws_size;

  char* ws = (char*)d_ws;
  size_t off = 0;
  auto alloc = [&](size_t bytes){ void* p = ws + off; off += (bytes + 255) & ~(size_t)255; return p; };
  float* lv    = (float*)alloc((size_t)N_TOT * 4);
  float* tvp   = (float*)alloc((size_t)2 * N_TOT * 4);  // [2][N] bn-halves; [0] reused as w
  float* maxlw = (float*)alloc(NUM_GROUP * 4);
  float* Zw    = (float*)alloc(NUM_GROUP * 4);
  int*   cand  = (int*)alloc(NUM_GROUP * 32 * 4);
  float* ekey  = (float*)alloc(NUM_GROUP * 32 * 4);
  float* emid  = (float*)alloc((size_t)NUM_GROUP * 32 * MDIM * 4);
  float* bagp  = (float*)alloc((size_t)NUM_GROUP * 64 * MDIM * 4);
  unsigned short* W1b  = (unsigned short*)alloc((size_t)MDIM * IN_CHN * 2);
  unsigned short* Wa1b = (unsigned short*)alloc((size_t)ATT_D * MDIM * 2);
  unsigned short* midb = (unsigned short*)alloc((size_t)N_TOT * MDIM * 2);
  float* w = tvp;  // tvp fully consumed into keys inside kselect before w is written

  kconv<<<2304, 256, 0, stream>>>(W1, Wa1, W1b, Wa1b);
  kgemm_mid<<<1564, 512, 0, stream>>>(idxf, tfeat, W1b, b1, Wc, midb, tvp);
  kattn<<<782, 256, 0, stream>>>(midb, Wa1b, ba1, Wa2, ba2, lv);
  kselect<<<8, 256, 0, stream>>>(lv, tvp, maxlw, Zw, cand, w);
  kexact<<<256, 256, 0, stream>>>(idxf, tfeat, W1, b1, Wa1, ba1, Wa2, ba2, Wc, cand, maxlw, emid, ekey);
  kbag<<<512, 256, 0, stream>>>(midb, w, bagp);
  kfinal<<<8, 256, 0, stream>>>(bagp, Wc, bc, emid, ekey, cand, out);
}

// Round 18
// 572.390 us; speedup vs baseline: 1.2325x; 1.0876x over previous
//
#include <hip/hip_runtime.h>
#include <stdint.h>

#define N_TOT 100000
#define IN_CHN 1024
#define MDIM 512
#define ATT_D 128
#define NUM_GROUP 8
#define GROUP_SIZE 12500
#define SEGB 196   // rows per kbag segment (64 segs/group)
#define PSEG 1563  // rows per kpsel partition (8 parts/group)

typedef __bf16 bf16x8 __attribute__((ext_vector_type(8)));
typedef float f32x4 __attribute__((ext_vector_type(4)));
typedef unsigned short u16x8 __attribute__((ext_vector_type(8)));

__device__ __forceinline__ unsigned short f2bf(float x){
  union { float f; unsigned u; } v; v.f = x;
  unsigned r = v.u + 0x7fffu + ((v.u >> 16) & 1u);
  return (unsigned short)(r >> 16);
}
__device__ __forceinline__ float bf2f(unsigned short h){
  union { unsigned u; float f; } v; v.u = ((unsigned)h) << 16; return v.f;
}
__device__ __forceinline__ void gload16(const void* g, void* l){
  __builtin_amdgcn_global_load_lds(
      (const __attribute__((address_space(1))) unsigned int*)g,
      (__attribute__((address_space(3))) unsigned int*)l, 16, 0, 0);
}

// ---------------- weight conversion f32 -> bf16 ----------------
__global__ __launch_bounds__(256) void kconv(const float* __restrict__ W1,
                                             const float* __restrict__ Wa1,
                                             unsigned short* __restrict__ W1b,
                                             unsigned short* __restrict__ Wa1b){
  int i = blockIdx.x * 256 + threadIdx.x;
  if (i < MDIM * IN_CHN) W1b[i] = f2bf(W1[i]);
  else {
    int j = i - MDIM * IN_CHN;
    if (j < ATT_D * MDIM) Wa1b[j] = f2bf(Wa1[j]);
  }
}

// ---------------- main gather+GEMM + fused tv-partials ----------------
__global__ __launch_bounds__(512) void kgemm_mid(const int* __restrict__ idxf,
                                                 const float* __restrict__ tfeat,
                                                 const unsigned short* __restrict__ W1b,
                                                 const float* __restrict__ b1,
                                                 const float* __restrict__ Wc,
                                                 unsigned short* __restrict__ midb,
                                                 float* __restrict__ tvp){
  __shared__ alignas(16) float Af[128 * 32];
  __shared__ alignas(16) unsigned short Bs[256 * 32];
  __shared__ int gsm[128];
  __shared__ float dcol[256];
  __shared__ float tvacc[128][4];
  int tid = threadIdx.x;
  int xcd = blockIdx.x & 7, idx = blockIdx.x >> 3;
  int tile = (xcd < 4 ? xcd * 196 : 4 * 196 + (xcd - 4) * 195) + idx;
  int bn = tile & 1, bm = tile >> 1;
  int m0 = bm * 128, n0 = bn * 256;
  if (tid < 128){ int r = m0 + tid; gsm[tid] = idxf[r < N_TOT ? r : 0]; }
  if (tid >= 128 && tid < 384){
    int c = tid - 128;
    dcol[c] = Wc[512 + n0 + c] - Wc[n0 + c];
  }
  __syncthreads();

  int w = tid >> 6, l = tid & 63;
  int l16 = tid & 15, hi = (tid >> 4) & 3;
  int wm = w >> 2, wn = w & 3;

  const float* asrc[2]; int adst[2];
  #pragma unroll
  for (int q = 0; q < 2; q++){
    int rowl = q * 64 + w * 8 + (l >> 3);
    asrc[q] = tfeat + (size_t)gsm[rowl] * IN_CHN + (((l & 7) ^ (l >> 3)) << 2);
    adst[q] = (q * 64 + w * 8) * 32;
  }
  const unsigned short* bsrc[2]; int bdst[2];
  #pragma unroll
  for (int q = 0; q < 2; q++){
    int rowl = q * 128 + w * 16 + (l >> 2);
    bsrc[q] = W1b + (size_t)(n0 + rowl) * IN_CHN + (((l & 3) ^ ((l >> 3) & 3)) << 3);
    bdst[q] = (q * 128 + w * 16) * 32;
  }

  f32x4 acc[4][4];
  #pragma unroll
  for (int a = 0; a < 4; a++)
    #pragma unroll
    for (int b = 0; b < 4; b++) acc[a][b] = (f32x4){0.f, 0.f, 0.f, 0.f};

  int r7 = l16 & 7;
  int b3 = (l16 >> 1) & 3;

  for (int s = 0; s < 32; s++){
    __syncthreads();
    #pragma unroll
    for (int q = 0; q < 2; q++){
      gload16(asrc[q] + s * 32, &Af[adst[q]]);
      gload16(bsrc[q] + s * 32, &Bs[bdst[q]]);
    }
    __syncthreads();

    bf16x8 af[4], bfr[4];
    #pragma unroll
    for (int a = 0; a < 4; a++){
      int row = wm * 64 + a * 16 + l16;
      f32x4 lo  = *(const f32x4*)&Af[row * 32 + (((2 * hi) ^ r7) << 2)];
      f32x4 hi4 = *(const f32x4*)&Af[row * 32 + (((2 * hi + 1) ^ r7) << 2)];
      bf16x8 pk;
      pk[0] = (__bf16)lo[0]; pk[1] = (__bf16)lo[1]; pk[2] = (__bf16)lo[2]; pk[3] = (__bf16)lo[3];
      pk[4] = (__bf16)hi4[0]; pk[5] = (__bf16)hi4[1]; pk[6] = (__bf16)hi4[2]; pk[7] = (__bf16)hi4[3];
      af[a] = pk;
    }
    #pragma unroll
    for (int b = 0; b < 4; b++){
      int row = wn * 64 + b * 16 + l16;
      bfr[b] = *(const bf16x8*)&Bs[row * 32 + ((hi ^ b3) << 3)];
    }
    #pragma unroll
    for (int a = 0; a < 4; a++)
      #pragma unroll
      for (int b = 0; b < 4; b++)
        acc[a][b] = __builtin_amdgcn_mfma_f32_16x16x32_bf16(af[a], bfr[b], acc[a][b], 0, 0, 0);
  }

  float biasv[4];
  #pragma unroll
  for (int b = 0; b < 4; b++) biasv[b] = b1[n0 + wn * 64 + b * 16 + l16];
  #pragma unroll
  for (int a = 0; a < 4; a++){
    #pragma unroll
    for (int q = 0; q < 4; q++){
      int row = m0 + wm * 64 + a * 16 + hi * 4 + q;
      float t = 0.f;
      #pragma unroll
      for (int b = 0; b < 4; b++){
        int colL = wn * 64 + b * 16 + l16;
        float v = fmaxf(acc[a][b][q] + biasv[b], 0.f);
        t += v * dcol[colL];
        if (row < N_TOT) midb[(size_t)row * MDIM + n0 + colL] = f2bf(v);
      }
      t += __shfl_xor(t, 1); t += __shfl_xor(t, 2);
      t += __shfl_xor(t, 4); t += __shfl_xor(t, 8);
      if (l16 == 0) tvacc[wm * 64 + a * 16 + hi * 4 + q][wn] = t;
    }
  }
  __syncthreads();
  if (tid < 128){
    int row = m0 + tid;
    if (row < N_TOT)
      tvp[(size_t)bn * N_TOT + row] = tvacc[tid][0] + tvacc[tid][1] + tvacc[tid][2] + tvacc[tid][3];
  }
}

// ---------------- attention MLP (lv only) ----------------
__global__ __launch_bounds__(256) void kattn(const unsigned short* __restrict__ midb,
                                             const unsigned short* __restrict__ Wa1b,
                                             const float* __restrict__ ba1,
                                             const float* __restrict__ Wa2,
                                             const float* __restrict__ ba2,
                                             float* __restrict__ lv){
  __shared__ alignas(16) unsigned short Asm[128 * 64];
  __shared__ alignas(16) unsigned short Bsm[128 * 64];
  __shared__ float part[128][2];
  int tid = threadIdx.x;
  int m0 = blockIdx.x * 128;

  int w = tid >> 6, l = tid & 63;
  int l16 = tid & 15, hi = (tid >> 4) & 3;
  int wm = tid >> 7, wn = (tid >> 6) & 1;
  int scw = (l & 7) ^ (l >> 3);

  const unsigned short *asrc[4], *bsrc[4];
  int dsto[4];
  #pragma unroll
  for (int q = 0; q < 4; q++){
    int rowl = q * 32 + w * 8 + (l >> 3);
    asrc[q] = midb + (size_t)(m0 + rowl) * MDIM + scw * 8;
    bsrc[q] = Wa1b + (size_t)rowl * MDIM + scw * 8;
    dsto[q] = (q * 32 + w * 8) * 64;
  }

  f32x4 acc[4][4];
  #pragma unroll
  for (int a = 0; a < 4; a++)
    #pragma unroll
    for (int b = 0; b < 4; b++) acc[a][b] = (f32x4){0.f, 0.f, 0.f, 0.f};
  int r7 = l16 & 7;

  for (int s = 0; s < 8; s++){
    __syncthreads();
    #pragma unroll
    for (int q = 0; q < 4; q++){
      gload16(asrc[q] + s * 64, &Asm[dsto[q]]);
      gload16(bsrc[q] + s * 64, &Bsm[dsto[q]]);
    }
    __syncthreads();
    #pragma unroll
    for (int ks = 0; ks < 2; ks++){
      bf16x8 af[4], bfr[4];
      #pragma unroll
      for (int a = 0; a < 4; a++){
        int row = wm * 64 + a * 16 + l16;
        af[a] = *(const bf16x8*)&Asm[row * 64 + (((ks * 4 + hi) ^ r7) << 3)];
      }
      #pragma unroll
      for (int b = 0; b < 4; b++){
        int row = wn * 64 + b * 16 + l16;
        bfr[b] = *(const bf16x8*)&Bsm[row * 64 + (((ks * 4 + hi) ^ r7) << 3)];
      }
      #pragma unroll
      for (int a = 0; a < 4; a++)
        #pragma unroll
        for (int b = 0; b < 4; b++)
          acc[a][b] = __builtin_amdgcn_mfma_f32_16x16x32_bf16(af[a], bfr[b], acc[a][b], 0, 0, 0);
    }
  }
  #pragma unroll
  for (int a = 0; a < 4; a++){
    #pragma unroll
    for (int q = 0; q < 4; q++){
      float v = 0.f;
      #pragma unroll
      for (int b = 0; b < 4; b++){
        int col = wn * 64 + b * 16 + l16;
        v += tanhf(acc[a][b][q] + ba1[col]) * Wa2[col];
      }
      #pragma unroll
      for (int off = 1; off < 16; off <<= 1) v += __shfl_xor(v, off);
      if (l16 == 0) part[wm * 64 + a * 16 + hi * 4 + q][wn] = v;
    }
  }
  __syncthreads();
  if (tid < 128){
    int row = m0 + tid;
    if (row < N_TOT) lv[row] = part[tid][0] + part[tid][1] + ba2[0];
  }
}

// ---------------- group stats + softmax weights ----------------
__global__ __launch_bounds__(256) void kstat(const float* __restrict__ lv,
                                             float* __restrict__ maxlw, float* __restrict__ Zw,
                                             float* __restrict__ w){
  __shared__ float rk[256];
  __shared__ float sbc;
  int g = blockIdx.x, tid = threadIdx.x;
  const float* lg = lv + (size_t)g * GROUP_SIZE;
  float mx = -1e30f;
  for (int i = tid; i < GROUP_SIZE; i += 256) mx = fmaxf(mx, lg[i]);
  rk[tid] = mx; __syncthreads();
  for (int s = 128; s > 0; s >>= 1){ if (tid < s) rk[tid] = fmaxf(rk[tid], rk[tid + s]); __syncthreads(); }
  if (tid == 0) sbc = rk[0];
  __syncthreads();
  float maxl = sbc;
  float z = 0.f;
  for (int i = tid; i < GROUP_SIZE; i += 256) z += expf(lg[i] - maxl);
  rk[tid] = z; __syncthreads();
  for (int s = 128; s > 0; s >>= 1){ if (tid < s) rk[tid] += rk[tid + s]; __syncthreads(); }
  if (tid == 0){ maxlw[g] = maxl; Zw[g] = rk[0]; }
  __syncthreads();
  float invZ = 1.0f / rk[0];
  for (int i = tid; i < GROUP_SIZE; i += 256)
    w[(size_t)g * GROUP_SIZE + i] = expf(lg[i] - maxl) * invZ;
}

// ---------------- partition-level top/bottom-16 (key = w * t, ref-exact order) ----------------
__global__ __launch_bounds__(256) void kpsel(const float* __restrict__ w,
                                             const float* __restrict__ tvp,
                                             float* __restrict__ ptk, int* __restrict__ pti,
                                             float* __restrict__ pbk, int* __restrict__ pbi){
  __shared__ float keys[PSEG];
  __shared__ float rk[256];
  __shared__ int rj[256];
  __shared__ int pslot[16];
  __shared__ float pvalk[16];
  int bid = blockIdx.x, tid = threadIdx.x;
  int g = bid >> 3, p = bid & 7;
  int i0 = p * PSEG;
  int nr = GROUP_SIZE - i0; if (nr > PSEG) nr = PSEG;
  size_t base = (size_t)g * GROUP_SIZE;
  for (int j = tid; j < nr; j += 256){
    size_t gi = base + i0 + j;
    keys[j] = w[gi] * (tvp[gi] + tvp[N_TOT + gi]);
  }
  __syncthreads();
  // ---- top-16 (desc key, asc idx) ----
  for (int it = 0; it < 16; it++){
    float bk = -1e30f; int bj = 0x7fffffff;
    for (int j = tid; j < nr; j += 256){
      float k = keys[j];
      if (k > bk || (k == bk && j < bj)){ bk = k; bj = j; }
    }
    rk[tid] = bk; rj[tid] = bj;
    __syncthreads();
    if (tid < 64){
      float k = rk[tid]; int j = rj[tid];
      #pragma unroll
      for (int o = 64; o < 256; o += 64){
        float ko = rk[tid + o]; int jo = rj[tid + o];
        if (ko > k || (ko == k && jo < j)){ k = ko; j = jo; }
      }
      #pragma unroll
      for (int off = 32; off > 0; off >>= 1){
        float ko = __shfl_xor(k, off); int jo = __shfl_xor(j, off);
        if (ko > k || (ko == k && jo < j)){ k = ko; j = jo; }
      }
      if (tid == 0){
        ptk[bid * 16 + it] = k; pti[bid * 16 + it] = i0 + j;
        pslot[it] = j; pvalk[it] = k;
        keys[j] = -1e30f;
      }
    }
    __syncthreads();
  }
  if (tid < 16) keys[pslot[tid]] = pvalk[tid];   // restore for bottom pass
  __syncthreads();
  // ---- bottom-16 (asc key, desc idx) ----
  for (int it = 0; it < 16; it++){
    float bk = 1e30f; int bj = -1;
    for (int j = tid; j < nr; j += 256){
      float k = keys[j];
      if (k < bk || (k == bk && j > bj)){ bk = k; bj = j; }
    }
    rk[tid] = bk; rj[tid] = bj;
    __syncthreads();
    if (tid < 64){
      float k = rk[tid]; int j = rj[tid];
      #pragma unroll
      for (int o = 64; o < 256; o += 64){
        float ko = rk[tid + o]; int jo = rj[tid + o];
        if (ko < k || (ko == k && jo > j)){ k = ko; j = jo; }
      }
      #pragma unroll
      for (int off = 32; off > 0; off >>= 1){
        float ko = __shfl_xor(k, off); int jo = __shfl_xor(j, off);
        if (ko < k || (ko == k && jo > j)){ k = ko; j = jo; }
      }
      if (tid == 0){
        pbk[bid * 16 + it] = k; pbi[bid * 16 + it] = i0 + j;
        keys[j] = 1e30f;
      }
    }
    __syncthreads();
  }
}

// ---------------- merge 8x16 partition candidates -> cand[32] per group ----------------
__global__ __launch_bounds__(256) void kmerge(const float* __restrict__ ptk, const int* __restrict__ pti,
                                              const float* __restrict__ pbk, const int* __restrict__ pbi,
                                              int* __restrict__ cand){
  __shared__ float ck[128];
  __shared__ int ci[128];
  __shared__ float rk[256];
  __shared__ int ri[256];
  __shared__ int rs[256];
  int g = blockIdx.x, tid = threadIdx.x;
  if (tid < 128){ ck[tid] = ptk[g * 128 + tid]; ci[tid] = pti[g * 128 + tid]; }
  __syncthreads();
  for (int it = 0; it < 16; it++){
    float bk = (tid < 128) ? ck[tid] : -1e30f;
    int bi = (tid < 128) ? ci[tid] : 0x7fffffff;
    rk[tid] = bk; ri[tid] = bi; rs[tid] = tid;
    __syncthreads();
    if (tid < 64){
      float k = rk[tid]; int ii = ri[tid], ss = rs[tid];
      #pragma unroll
      for (int o = 64; o < 256; o += 64){
        float ko = rk[tid + o]; int io = ri[tid + o]; int so = rs[tid + o];
        if (ko > k || (ko == k && io < ii)){ k = ko; ii = io; ss = so; }
      }
      #pragma unroll
      for (int off = 32; off > 0; off >>= 1){
        float ko = __shfl_xor(k, off); int io = __shfl_xor(ii, off); int so = __shfl_xor(ss, off);
        if (ko > k || (ko == k && io < ii)){ k = ko; ii = io; ss = so; }
      }
      if (tid == 0){ cand[g * 32 + it] = ii; ck[ss] = -1e30f; }
    }
    __syncthreads();
  }
  if (tid < 128){ ck[tid] = pbk[g * 128 + tid]; ci[tid] = pbi[g * 128 + tid]; }
  __syncthreads();
  for (int it = 0; it < 16; it++){
    float bk = (tid < 128) ? ck[tid] : 1e30f;
    int bi = (tid < 128) ? ci[tid] : -1;
    rk[tid] = bk; ri[tid] = bi; rs[tid] = tid;
    __syncthreads();
    if (tid < 64){
      float k = rk[tid]; int ii = ri[tid], ss = rs[tid];
      #pragma unroll
      for (int o = 64; o < 256; o += 64){
        float ko = rk[tid + o]; int io = ri[tid + o]; int so = rs[tid + o];
        if (ko < k || (ko == k && io > ii)){ k = ko; ii = io; ss = so; }
      }
      #pragma unroll
      for (int off = 32; off > 0; off >>= 1){
        float ko = __shfl_xor(k, off); int io = __shfl_xor(ii, off); int so = __shfl_xor(ss, off);
        if (ko < k || (ko == k && io > ii)){ k = ko; ii = io; ss = so; }
      }
      if (tid == 0){ cand[g * 32 + 16 + it] = ii; ck[ss] = 1e30f; }
    }
    __syncthreads();
  }
}

// ---------------- exact f32 recompute of 256 candidate rows ----------------
__global__ __launch_bounds__(256) void kexact(const int* __restrict__ idxf,
                                              const float* __restrict__ tfeat,
                                              const float* __restrict__ W1,
                                              const float* __restrict__ b1,
                                              const float* __restrict__ Wa1,
                                              const float* __restrict__ ba1,
                                              const float* __restrict__ Wa2,
                                              const float* __restrict__ ba2,
                                              const float* __restrict__ Wc,
                                              const int* __restrict__ cand,
                                              const float* __restrict__ maxlw,
                                              float* __restrict__ emid, float* __restrict__ ekey){
  __shared__ float subs[1024];
  __shared__ float midc[512];
  __shared__ float hs[128];
  __shared__ float red[256];
  __shared__ float tsh;
  int bid = blockIdx.x; int g = bid >> 5, c = bid & 31; int tid = threadIdx.x;
  int s = cand[g * 32 + c];
  int inst = idxf[g * GROUP_SIZE + s];
  ((float4*)subs)[tid] = ((const float4*)(tfeat + (size_t)inst * IN_CHN))[tid];
  __syncthreads();

  float a0 = b1[tid], a1 = b1[tid + 256];
  const float4* w0 = (const float4*)(W1 + (size_t)tid * IN_CHN);
  const float4* w1 = (const float4*)(W1 + ((size_t)tid + 256) * IN_CHN);
  const float4* s4 = (const float4*)subs;
  #pragma unroll 4
  for (int k = 0; k < 256; k++){
    float4 sv = s4[k], wva = w0[k], wvb = w1[k];
    a0 += sv.x * wva.x + sv.y * wva.y + sv.z * wva.z + sv.w * wva.w;
    a1 += sv.x * wvb.x + sv.y * wvb.y + sv.z * wvb.z + sv.w * wvb.w;
  }
  a0 = fmaxf(a0, 0.f); a1 = fmaxf(a1, 0.f);
  midc[tid] = a0; midc[tid + 256] = a1;
  size_t eo = (size_t)(g * 32 + c) * MDIM;
  emid[eo + tid] = a0; emid[eo + tid + 256] = a1;
  __syncthreads();

  if (tid < 128){
    const float4* wr = (const float4*)(Wa1 + (size_t)tid * MDIM);
    const float4* m4 = (const float4*)midc;
    float h = ba1[tid];
    #pragma unroll 4
    for (int j = 0; j < 128; j++){
      float4 mv = m4[j], wv = wr[j];
      h += mv.x * wv.x + mv.y * wv.y + mv.z * wv.z + mv.w * wv.w;
    }
    hs[tid] = tanhf(h) * Wa2[tid];
  }
  __syncthreads();

  float tp = midc[tid] * (Wc[512 + tid] - Wc[tid]) + midc[tid + 256] * (Wc[768 + tid] - Wc[256 + tid]);
  red[tid] = tp; __syncthreads();
  for (int st = 128; st > 0; st >>= 1){ if (tid < st) red[tid] += red[tid + st]; __syncthreads(); }
  if (tid == 0) tsh = red[0];
  __syncthreads();
  red[tid] = (tid < 128) ? hs[tid] : 0.f; __syncthreads();
  for (int st = 128; st > 0; st >>= 1){ if (tid < st) red[tid] += red[tid + st]; __syncthreads(); }
  if (tid == 0){
    float lval = red[0] + ba2[0];
    ekey[g * 32 + c] = expf(lval - maxlw[g]) * tsh;
  }
}

// ---------------- weighted bag-sum: 64 segments x 8 groups, 16B/lane ----------------
__global__ __launch_bounds__(256) void kbag(const unsigned short* __restrict__ midb,
                                            const float* __restrict__ w,
                                            float* __restrict__ bagp){
  __shared__ float wl[SEGB];
  __shared__ float red[4][512];
  int g = blockIdx.x >> 6, seg = blockIdx.x & 63, tid = threadIdx.x;
  int rg = tid >> 6, lane = tid & 63;
  int i0 = seg * SEGB;
  int nr = GROUP_SIZE - i0; if (nr > SEGB) nr = SEGB;
  size_t base = (size_t)g * GROUP_SIZE;
  if (tid < nr) wl[tid] = w[base + i0 + tid];
  __syncthreads();
  float a[8] = {0.f,0.f,0.f,0.f,0.f,0.f,0.f,0.f};
  const unsigned short* mp = midb + (base + i0) * MDIM + lane * 8;
  for (int i = rg; i < nr; i += 4){
    float wi = wl[i];
    u16x8 v = *(const u16x8*)(mp + (size_t)i * MDIM);
    #pragma unroll
    for (int e = 0; e < 8; e++) a[e] += wi * bf2f((unsigned short)v[e]);
  }
  #pragma unroll
  for (int e = 0; e < 8; e++) red[rg][lane * 8 + e] = a[e];
  __syncthreads();
  if (rg == 0){
    float* dst = bagp + (size_t)blockIdx.x * MDIM + lane * 8;
    #pragma unroll
    for (int e = 0; e < 8; e++){
      int c = lane * 8 + e;
      dst[e] = red[0][c] + red[1][c] + red[2][c] + red[3][c];
    }
  }
}

// ---------------- final: exact re-rank, preds, feature copy — FLOAT32 output ----------------
__global__ __launch_bounds__(256) void kfinal(const float* __restrict__ bagp,
                                              const float* __restrict__ Wc,
                                              const float* __restrict__ bc,
                                              const float* __restrict__ emid,
                                              const float* __restrict__ ekey,
                                              const int* __restrict__ cand,
                                              float* __restrict__ out){
  __shared__ float k32[32];
  __shared__ int s32[32];
  __shared__ int ordv[32];
  __shared__ float r0[256], r1[256];
  int g = blockIdx.x, tid = threadIdx.x;
  if (tid < 32){ k32[tid] = ekey[g * 32 + tid]; s32[tid] = cand[g * 32 + tid]; }
  __syncthreads();
  if (tid == 0){
    unsigned used = 0;
    for (int a = 0; a < 32; a++){
      int best = -1;
      for (int b = 0; b < 32; b++){
        if ((used >> b) & 1u) continue;
        if (best < 0 || k32[b] > k32[best] || (k32[b] == k32[best] && s32[b] < s32[best])) best = b;
      }
      used |= 1u << best;
      ordv[a] = best;
    }
  }
  float p0 = 0.f, p1 = 0.f;
  for (int j = tid; j < 512; j += 256){
    float bv = 0.f;
    for (int s2 = 0; s2 < 64; s2++) bv += bagp[(size_t)(g * 64 + s2) * MDIM + j];
    p0 += bv * Wc[j];
    p1 += bv * Wc[512 + j];
  }
  r0[tid] = p0; r1[tid] = p1; __syncthreads();
  for (int s = 128; s > 0; s >>= 1){ if (tid < s){ r0[tid] += r0[tid + s]; r1[tid] += r1[tid + s]; } __syncthreads(); }
  if (tid == 0){
    out[g * 2 + 0] = r0[0] + bc[0];
    out[g * 2 + 1] = r1[0] + bc[1];
  }
  __syncthreads();
  for (int p = 0; p < 8; p++){
    int cc = ordv[p < 4 ? p : 24 + p];
    const float* src = emid + (size_t)(g * 32 + cc) * MDIM;
    float* dst = out + 16 + (size_t)(g * 8 + p) * MDIM;
    for (int j = tid; j < 512; j += 256) dst[j] = src[j];
  }
}

extern "C" void kernel_launch(void* const* d_in, const int* in_sizes, int n_in,
                              void* d_out, int out_size, void* d_ws, size_t ws_size,
                              hipStream_t stream){
  const int*   idxf = (const int*)d_in[0];
  const float* tfeat= (const float*)d_in[1];
  const float* W1   = (const float*)d_in[2];
  const float* b1   = (const float*)d_in[3];
  const float* Wa1  = (const float*)d_in[4];
  const float* ba1  = (const float*)d_in[5];
  const float* Wa2  = (const float*)d_in[6];
  const float* ba2  = (const float*)d_in[7];
  const float* Wc   = (const float*)d_in[8];
  const float* bc   = (const float*)d_in[9];
  float* out = (float*)d_out;
  (void)in_sizes; (void)n_in; (void)out_size; (void)ws_size;

  char* ws = (char*)d_ws;
  size_t off = 0;
  auto alloc = [&](size_t bytes){ void* p = ws + off; off += (bytes + 255) & ~(size_t)255; return p; };
  float* lv    = (float*)alloc((size_t)N_TOT * 4);
  float* tvp   = (float*)alloc((size_t)2 * N_TOT * 4);
  float* wsm   = (float*)alloc((size_t)N_TOT * 4);     // softmax weights (separate: tvp stays live)
  float* maxlw = (float*)alloc(NUM_GROUP * 4);
  float* Zw    = (float*)alloc(NUM_GROUP * 4);
  int*   cand  = (int*)alloc(NUM_GROUP * 32 * 4);
  float* ekey  = (float*)alloc(NUM_GROUP * 32 * 4);
  float* ptk   = (float*)alloc(64 * 16 * 4);
  int*   pti   = (int*)alloc(64 * 16 * 4);
  float* pbk   = (float*)alloc(64 * 16 * 4);
  int*   pbi   = (int*)alloc(64 * 16 * 4);
  float* emid  = (float*)alloc((size_t)NUM_GROUP * 32 * MDIM * 4);
  float* bagp  = (float*)alloc((size_t)NUM_GROUP * 64 * MDIM * 4);
  unsigned short* W1b  = (unsigned short*)alloc((size_t)MDIM * IN_CHN * 2);
  unsigned short* Wa1b = (unsigned short*)alloc((size_t)ATT_D * MDIM * 2);
  unsigned short* midb = (unsigned short*)alloc((size_t)N_TOT * MDIM * 2);

  kconv<<<2304, 256, 0, stream>>>(W1, Wa1, W1b, Wa1b);
  kgemm_mid<<<1564, 512, 0, stream>>>(idxf, tfeat, W1b, b1, Wc, midb, tvp);
  kattn<<<782, 256, 0, stream>>>(midb, Wa1b, ba1, Wa2, ba2, lv);
  kstat<<<8, 256, 0, stream>>>(lv, maxlw, Zw, wsm);
  kpsel<<<64, 256, 0, stream>>>(wsm, tvp, ptk, pti, pbk, pbi);
  kmerge<<<8, 256, 0, stream>>>(ptk, pti, pbk, pbi, cand);
  kexact<<<256, 256, 0, stream>>>(idxf, tfeat, W1, b1, Wa1, ba1, Wa2, ba2, Wc, cand, maxlw, emid, ekey);
  kbag<<<512, 256, 0, stream>>>(midb, wsm, bagp);
  kfinal<<<8, 256, 0, stream>>>(bagp, Wc, bc, emid, ekey, cand, out);
}

// Round 19
// 567.729 us; speedup vs baseline: 1.2426x; 1.0082x over previous
//
#include <hip/hip_runtime.h>
#include <stdint.h>

#define N_TOT 100000
#define IN_CHN 1024
#define MDIM 512
#define ATT_D 128
#define NUM_GROUP 8
#define GROUP_SIZE 12500
#define SEGB 196   // rows per kbag segment (64 segs/group)
#define PSEG 1563  // rows per kpsel partition (8 parts/group)

typedef __bf16 bf16x8 __attribute__((ext_vector_type(8)));
typedef float f32x4 __attribute__((ext_vector_type(4)));
typedef unsigned short u16x8 __attribute__((ext_vector_type(8)));

__device__ __forceinline__ unsigned short f2bf(float x){
  union { float f; unsigned u; } v; v.f = x;
  unsigned r = v.u + 0x7fffu + ((v.u >> 16) & 1u);
  return (unsigned short)(r >> 16);
}
__device__ __forceinline__ float bf2f(unsigned short h){
  union { unsigned u; float f; } v; v.u = ((unsigned)h) << 16; return v.f;
}
__device__ __forceinline__ void gload16(const void* g, void* l){
  __builtin_amdgcn_global_load_lds(
      (const __attribute__((address_space(1))) unsigned int*)g,
      (__attribute__((address_space(3))) unsigned int*)l, 16, 0, 0);
}

// ---------------- weight conversion f32 -> bf16 ----------------
__global__ __launch_bounds__(256) void kconv(const float* __restrict__ W1,
                                             const float* __restrict__ Wa1,
                                             unsigned short* __restrict__ W1b,
                                             unsigned short* __restrict__ Wa1b){
  int i = blockIdx.x * 256 + threadIdx.x;
  if (i < MDIM * IN_CHN) W1b[i] = f2bf(W1[i]);
  else {
    int j = i - MDIM * IN_CHN;
    if (j < ATT_D * MDIM) Wa1b[j] = f2bf(Wa1[j]);
  }
}

// ---------------- main gather+GEMM + fused tv-partials ----------------
__global__ __launch_bounds__(512) void kgemm_mid(const int* __restrict__ idxf,
                                                 const float* __restrict__ tfeat,
                                                 const unsigned short* __restrict__ W1b,
                                                 const float* __restrict__ b1,
                                                 const float* __restrict__ Wc,
                                                 unsigned short* __restrict__ midb,
                                                 float* __restrict__ tvp){
  __shared__ alignas(16) float Af[128 * 32];
  __shared__ alignas(16) unsigned short Bs[256 * 32];
  __shared__ int gsm[128];
  __shared__ float dcol[256];
  __shared__ float tvacc[128][4];
  int tid = threadIdx.x;
  int xcd = blockIdx.x & 7, idx = blockIdx.x >> 3;
  int tile = (xcd < 4 ? xcd * 196 : 4 * 196 + (xcd - 4) * 195) + idx;
  int bn = tile & 1, bm = tile >> 1;
  int m0 = bm * 128, n0 = bn * 256;
  if (tid < 128){ int r = m0 + tid; gsm[tid] = idxf[r < N_TOT ? r : 0]; }
  if (tid >= 128 && tid < 384){
    int c = tid - 128;
    dcol[c] = Wc[512 + n0 + c] - Wc[n0 + c];
  }
  __syncthreads();

  int w = tid >> 6, l = tid & 63;
  int l16 = tid & 15, hi = (tid >> 4) & 3;
  int wm = w >> 2, wn = w & 3;

  const float* asrc[2]; int adst[2];
  #pragma unroll
  for (int q = 0; q < 2; q++){
    int rowl = q * 64 + w * 8 + (l >> 3);
    asrc[q] = tfeat + (size_t)gsm[rowl] * IN_CHN + (((l & 7) ^ (l >> 3)) << 2);
    adst[q] = (q * 64 + w * 8) * 32;
  }
  const unsigned short* bsrc[2]; int bdst[2];
  #pragma unroll
  for (int q = 0; q < 2; q++){
    int rowl = q * 128 + w * 16 + (l >> 2);
    bsrc[q] = W1b + (size_t)(n0 + rowl) * IN_CHN + (((l & 3) ^ ((l >> 3) & 3)) << 3);
    bdst[q] = (q * 128 + w * 16) * 32;
  }

  f32x4 acc[4][4];
  #pragma unroll
  for (int a = 0; a < 4; a++)
    #pragma unroll
    for (int b = 0; b < 4; b++) acc[a][b] = (f32x4){0.f, 0.f, 0.f, 0.f};

  int r7 = l16 & 7;
  int b3 = (l16 >> 1) & 3;

  for (int s = 0; s < 32; s++){
    __syncthreads();
    #pragma unroll
    for (int q = 0; q < 2; q++){
      gload16(asrc[q] + s * 32, &Af[adst[q]]);
      gload16(bsrc[q] + s * 32, &Bs[bdst[q]]);
    }
    __syncthreads();

    bf16x8 af[4], bfr[4];
    #pragma unroll
    for (int a = 0; a < 4; a++){
      int row = wm * 64 + a * 16 + l16;
      f32x4 lo  = *(const f32x4*)&Af[row * 32 + (((2 * hi) ^ r7) << 2)];
      f32x4 hi4 = *(const f32x4*)&Af[row * 32 + (((2 * hi + 1) ^ r7) << 2)];
      bf16x8 pk;
      pk[0] = (__bf16)lo[0]; pk[1] = (__bf16)lo[1]; pk[2] = (__bf16)lo[2]; pk[3] = (__bf16)lo[3];
      pk[4] = (__bf16)hi4[0]; pk[5] = (__bf16)hi4[1]; pk[6] = (__bf16)hi4[2]; pk[7] = (__bf16)hi4[3];
      af[a] = pk;
    }
    #pragma unroll
    for (int b = 0; b < 4; b++){
      int row = wn * 64 + b * 16 + l16;
      bfr[b] = *(const bf16x8*)&Bs[row * 32 + ((hi ^ b3) << 3)];
    }
    #pragma unroll
    for (int a = 0; a < 4; a++)
      #pragma unroll
      for (int b = 0; b < 4; b++)
        acc[a][b] = __builtin_amdgcn_mfma_f32_16x16x32_bf16(af[a], bfr[b], acc[a][b], 0, 0, 0);
  }

  float biasv[4];
  #pragma unroll
  for (int b = 0; b < 4; b++) biasv[b] = b1[n0 + wn * 64 + b * 16 + l16];
  #pragma unroll
  for (int a = 0; a < 4; a++){
    #pragma unroll
    for (int q = 0; q < 4; q++){
      int row = m0 + wm * 64 + a * 16 + hi * 4 + q;
      float t = 0.f;
      #pragma unroll
      for (int b = 0; b < 4; b++){
        int colL = wn * 64 + b * 16 + l16;
        float v = fmaxf(acc[a][b][q] + biasv[b], 0.f);
        t += v * dcol[colL];
        if (row < N_TOT) midb[(size_t)row * MDIM + n0 + colL] = f2bf(v);
      }
      t += __shfl_xor(t, 1); t += __shfl_xor(t, 2);
      t += __shfl_xor(t, 4); t += __shfl_xor(t, 8);
      if (l16 == 0) tvacc[wm * 64 + a * 16 + hi * 4 + q][wn] = t;
    }
  }
  __syncthreads();
  if (tid < 128){
    int row = m0 + tid;
    if (row < N_TOT)
      tvp[(size_t)bn * N_TOT + row] = tvacc[tid][0] + tvacc[tid][1] + tvacc[tid][2] + tvacc[tid][3];
  }
}

// ---------------- attention MLP (lv only): 64-row tiles, 24KB LDS, high occupancy ----------------
__global__ __launch_bounds__(256) void kattn(const unsigned short* __restrict__ midb,
                                             const unsigned short* __restrict__ Wa1b,
                                             const float* __restrict__ ba1,
                                             const float* __restrict__ Wa2,
                                             const float* __restrict__ ba2,
                                             float* __restrict__ lv){
  __shared__ alignas(16) unsigned short Asm[64 * 64];    // 8 KB
  __shared__ alignas(16) unsigned short Bsm[128 * 64];   // 16 KB
  __shared__ float part[64][2];
  int tid = threadIdx.x;
  int m0 = blockIdx.x * 64;

  int w = tid >> 6, l = tid & 63;
  int l16 = tid & 15, hi = (tid >> 4) & 3;
  int wm = w >> 1, wn = w & 1;          // 2M x 2N wave grid; wave = 32 rows x 64 cols
  int scw = (l & 7) ^ (l >> 3);

  // A staging: 2 rounds; round q: rows q*32 + w*8 + (l>>3) (clamped)
  const unsigned short* asrc[2]; int adsto[2];
  #pragma unroll
  for (int q = 0; q < 2; q++){
    int rowl = q * 32 + w * 8 + (l >> 3);
    int rowc = m0 + rowl; if (rowc > N_TOT - 1) rowc = N_TOT - 1;
    asrc[q] = midb + (size_t)rowc * MDIM + scw * 8;
    adsto[q] = (q * 32 + w * 8) * 64;
  }
  // B staging: 4 rounds; round q: rows q*32 + w*8 + (l>>3) of Wa1b (128 rows)
  const unsigned short* bsrc[4]; int bdsto[4];
  #pragma unroll
  for (int q = 0; q < 4; q++){
    int rowl = q * 32 + w * 8 + (l >> 3);
    bsrc[q] = Wa1b + (size_t)rowl * MDIM + scw * 8;
    bdsto[q] = (q * 32 + w * 8) * 64;
  }

  f32x4 acc[2][4];
  #pragma unroll
  for (int a = 0; a < 2; a++)
    #pragma unroll
    for (int b = 0; b < 4; b++) acc[a][b] = (f32x4){0.f, 0.f, 0.f, 0.f};
  int r7 = l16 & 7;

  for (int s = 0; s < 8; s++){
    __syncthreads();
    #pragma unroll
    for (int q = 0; q < 2; q++) gload16(asrc[q] + s * 64, &Asm[adsto[q]]);
    #pragma unroll
    for (int q = 0; q < 4; q++) gload16(bsrc[q] + s * 64, &Bsm[bdsto[q]]);
    __syncthreads();
    #pragma unroll
    for (int ks = 0; ks < 2; ks++){
      int rc = ((ks * 4 + hi) ^ r7) << 3;
      bf16x8 af[2], bfr[4];
      #pragma unroll
      for (int a = 0; a < 2; a++){
        int row = wm * 32 + a * 16 + l16;
        af[a] = *(const bf16x8*)&Asm[row * 64 + rc];
      }
      #pragma unroll
      for (int b = 0; b < 4; b++){
        int row = wn * 64 + b * 16 + l16;
        bfr[b] = *(const bf16x8*)&Bsm[row * 64 + rc];
      }
      #pragma unroll
      for (int a = 0; a < 2; a++)
        #pragma unroll
        for (int b = 0; b < 4; b++)
          acc[a][b] = __builtin_amdgcn_mfma_f32_16x16x32_bf16(af[a], bfr[b], acc[a][b], 0, 0, 0);
    }
  }
  #pragma unroll
  for (int a = 0; a < 2; a++){
    #pragma unroll
    for (int q = 0; q < 4; q++){
      float v = 0.f;
      #pragma unroll
      for (int b = 0; b < 4; b++){
        int col = wn * 64 + b * 16 + l16;
        v += tanhf(acc[a][b][q] + ba1[col]) * Wa2[col];
      }
      #pragma unroll
      for (int off = 1; off < 16; off <<= 1) v += __shfl_xor(v, off);
      if (l16 == 0) part[wm * 32 + a * 16 + hi * 4 + q][wn] = v;
    }
  }
  __syncthreads();
  if (tid < 64){
    int row = m0 + tid;
    if (row < N_TOT) lv[row] = part[tid][0] + part[tid][1] + ba2[0];
  }
}

// ---------------- group stats + softmax weights ----------------
__global__ __launch_bounds__(256) void kstat(const float* __restrict__ lv,
                                             float* __restrict__ maxlw, float* __restrict__ Zw,
                                             float* __restrict__ w){
  __shared__ float rk[256];
  __shared__ float sbc;
  int g = blockIdx.x, tid = threadIdx.x;
  const float* lg = lv + (size_t)g * GROUP_SIZE;
  float mx = -1e30f;
  for (int i = tid; i < GROUP_SIZE; i += 256) mx = fmaxf(mx, lg[i]);
  rk[tid] = mx; __syncthreads();
  for (int s = 128; s > 0; s >>= 1){ if (tid < s) rk[tid] = fmaxf(rk[tid], rk[tid + s]); __syncthreads(); }
  if (tid == 0) sbc = rk[0];
  __syncthreads();
  float maxl = sbc;
  float z = 0.f;
  for (int i = tid; i < GROUP_SIZE; i += 256) z += expf(lg[i] - maxl);
  rk[tid] = z; __syncthreads();
  for (int s = 128; s > 0; s >>= 1){ if (tid < s) rk[tid] += rk[tid + s]; __syncthreads(); }
  if (tid == 0){ maxlw[g] = maxl; Zw[g] = rk[0]; }
  __syncthreads();
  float invZ = 1.0f / rk[0];
  for (int i = tid; i < GROUP_SIZE; i += 256)
    w[(size_t)g * GROUP_SIZE + i] = expf(lg[i] - maxl) * invZ;
}

// ---------------- partition-level top/bottom-16 (key = w * t, ref-exact order) ----------------
__global__ __launch_bounds__(256) void kpsel(const float* __restrict__ w,
                                             const float* __restrict__ tvp,
                                             float* __restrict__ ptk, int* __restrict__ pti,
                                             float* __restrict__ pbk, int* __restrict__ pbi){
  __shared__ float keys[PSEG];
  __shared__ float rk[256];
  __shared__ int rj[256];
  __shared__ int pslot[16];
  __shared__ float pvalk[16];
  int bid = blockIdx.x, tid = threadIdx.x;
  int g = bid >> 3, p = bid & 7;
  int i0 = p * PSEG;
  int nr = GROUP_SIZE - i0; if (nr > PSEG) nr = PSEG;
  size_t base = (size_t)g * GROUP_SIZE;
  for (int j = tid; j < nr; j += 256){
    size_t gi = base + i0 + j;
    keys[j] = w[gi] * (tvp[gi] + tvp[N_TOT + gi]);
  }
  __syncthreads();
  for (int it = 0; it < 16; it++){
    float bk = -1e30f; int bj = 0x7fffffff;
    for (int j = tid; j < nr; j += 256){
      float k = keys[j];
      if (k > bk || (k == bk && j < bj)){ bk = k; bj = j; }
    }
    rk[tid] = bk; rj[tid] = bj;
    __syncthreads();
    if (tid < 64){
      float k = rk[tid]; int j = rj[tid];
      #pragma unroll
      for (int o = 64; o < 256; o += 64){
        float ko = rk[tid + o]; int jo = rj[tid + o];
        if (ko > k || (ko == k && jo < j)){ k = ko; j = jo; }
      }
      #pragma unroll
      for (int off = 32; off > 0; off >>= 1){
        float ko = __shfl_xor(k, off); int jo = __shfl_xor(j, off);
        if (ko > k || (ko == k && jo < j)){ k = ko; j = jo; }
      }
      if (tid == 0){
        ptk[bid * 16 + it] = k; pti[bid * 16 + it] = i0 + j;
        pslot[it] = j; pvalk[it] = k;
        keys[j] = -1e30f;
      }
    }
    __syncthreads();
  }
  if (tid < 16) keys[pslot[tid]] = pvalk[tid];
  __syncthreads();
  for (int it = 0; it < 16; it++){
    float bk = 1e30f; int bj = -1;
    for (int j = tid; j < nr; j += 256){
      float k = keys[j];
      if (k < bk || (k == bk && j > bj)){ bk = k; bj = j; }
    }
    rk[tid] = bk; rj[tid] = bj;
    __syncthreads();
    if (tid < 64){
      float k = rk[tid]; int j = rj[tid];
      #pragma unroll
      for (int o = 64; o < 256; o += 64){
        float ko = rk[tid + o]; int jo = rj[tid + o];
        if (ko < k || (ko == k && jo > j)){ k = ko; j = jo; }
      }
      #pragma unroll
      for (int off = 32; off > 0; off >>= 1){
        float ko = __shfl_xor(k, off); int jo = __shfl_xor(j, off);
        if (ko < k || (ko == k && jo > j)){ k = ko; j = jo; }
      }
      if (tid == 0){
        pbk[bid * 16 + it] = k; pbi[bid * 16 + it] = i0 + j;
        keys[j] = 1e30f;
      }
    }
    __syncthreads();
  }
}

// ---------------- merge 8x16 partition candidates -> cand[32] per group ----------------
__global__ __launch_bounds__(256) void kmerge(const float* __restrict__ ptk, const int* __restrict__ pti,
                                              const float* __restrict__ pbk, const int* __restrict__ pbi,
                                              int* __restrict__ cand){
  __shared__ float ck[128];
  __shared__ int ci[128];
  __shared__ float rk[256];
  __shared__ int ri[256];
  __shared__ int rs[256];
  int g = blockIdx.x, tid = threadIdx.x;
  if (tid < 128){ ck[tid] = ptk[g * 128 + tid]; ci[tid] = pti[g * 128 + tid]; }
  __syncthreads();
  for (int it = 0; it < 16; it++){
    float bk = (tid < 128) ? ck[tid] : -1e30f;
    int bi = (tid < 128) ? ci[tid] : 0x7fffffff;
    rk[tid] = bk; ri[tid] = bi; rs[tid] = tid;
    __syncthreads();
    if (tid < 64){
      float k = rk[tid]; int ii = ri[tid], ss = rs[tid];
      #pragma unroll
      for (int o = 64; o < 256; o += 64){
        float ko = rk[tid + o]; int io = ri[tid + o]; int so = rs[tid + o];
        if (ko > k || (ko == k && io < ii)){ k = ko; ii = io; ss = so; }
      }
      #pragma unroll
      for (int off = 32; off > 0; off >>= 1){
        float ko = __shfl_xor(k, off); int io = __shfl_xor(ii, off); int so = __shfl_xor(ss, off);
        if (ko > k || (ko == k && io < ii)){ k = ko; ii = io; ss = so; }
      }
      if (tid == 0){ cand[g * 32 + it] = ii; ck[ss] = -1e30f; }
    }
    __syncthreads();
  }
  if (tid < 128){ ck[tid] = pbk[g * 128 + tid]; ci[tid] = pbi[g * 128 + tid]; }
  __syncthreads();
  for (int it = 0; it < 16; it++){
    float bk = (tid < 128) ? ck[tid] : 1e30f;
    int bi = (tid < 128) ? ci[tid] : -1;
    rk[tid] = bk; ri[tid] = bi; rs[tid] = tid;
    __syncthreads();
    if (tid < 64){
      float k = rk[tid]; int ii = ri[tid], ss = rs[tid];
      #pragma unroll
      for (int o = 64; o < 256; o += 64){
        float ko = rk[tid + o]; int io = ri[tid + o]; int so = rs[tid + o];
        if (ko < k || (ko == k && io > ii)){ k = ko; ii = io; ss = so; }
      }
      #pragma unroll
      for (int off = 32; off > 0; off >>= 1){
        float ko = __shfl_xor(k, off); int io = __shfl_xor(ii, off); int so = __shfl_xor(ss, off);
        if (ko < k || (ko == k && io > ii)){ k = ko; ii = io; ss = so; }
      }
      if (tid == 0){ cand[g * 32 + 16 + it] = ii; ck[ss] = 1e30f; }
    }
    __syncthreads();
  }
}

// ---------------- exact f32 recompute: 4 candidates per block (W1 reuse x4) ----------------
__global__ __launch_bounds__(256) void kexact(const int* __restrict__ idxf,
                                              const float* __restrict__ tfeat,
                                              const float* __restrict__ W1,
                                              const float* __restrict__ b1,
                                              const float* __restrict__ Wa1,
                                              const float* __restrict__ ba1,
                                              const float* __restrict__ Wa2,
                                              const float* __restrict__ ba2,
                                              const float* __restrict__ Wc,
                                              const int* __restrict__ cand,
                                              const float* __restrict__ maxlw,
                                              float* __restrict__ emid, float* __restrict__ ekey){
  __shared__ float subs[4][1024];   // 16 KB
  __shared__ float midc[4][512];    // 8 KB
  __shared__ float hs[4][128];      // 2 KB
  __shared__ float red[256];
  __shared__ float tshs[4];
  int c0 = blockIdx.x * 4;          // 4 candidates, all within one group (32 % 4 == 0)
  int g = c0 >> 5;
  int tid = threadIdx.x;
  #pragma unroll
  for (int cc = 0; cc < 4; cc++){
    int s = cand[c0 + cc];
    int inst = idxf[g * GROUP_SIZE + s];
    ((float4*)subs[cc])[tid] = ((const float4*)(tfeat + (size_t)inst * IN_CHN))[tid];
  }
  __syncthreads();

  float a0[4], a1[4];
  #pragma unroll
  for (int cc = 0; cc < 4; cc++){ a0[cc] = b1[tid]; a1[cc] = b1[tid + 256]; }
  const float4* w0 = (const float4*)(W1 + (size_t)tid * IN_CHN);
  const float4* w1 = (const float4*)(W1 + ((size_t)tid + 256) * IN_CHN);
  #pragma unroll 2
  for (int k = 0; k < 256; k++){
    float4 wva = w0[k], wvb = w1[k];
    #pragma unroll
    for (int cc = 0; cc < 4; cc++){
      float4 sv = ((const float4*)subs[cc])[k];
      a0[cc] += sv.x * wva.x + sv.y * wva.y + sv.z * wva.z + sv.w * wva.w;
      a1[cc] += sv.x * wvb.x + sv.y * wvb.y + sv.z * wvb.z + sv.w * wvb.w;
    }
  }
  #pragma unroll
  for (int cc = 0; cc < 4; cc++){
    float v0 = fmaxf(a0[cc], 0.f), v1 = fmaxf(a1[cc], 0.f);
    midc[cc][tid] = v0; midc[cc][tid + 256] = v1;
    size_t eo = (size_t)(c0 + cc) * MDIM;
    emid[eo + tid] = v0; emid[eo + tid + 256] = v1;
  }
  __syncthreads();

  if (tid < 128){
    const float4* wr = (const float4*)(Wa1 + (size_t)tid * MDIM);
    float h[4];
    #pragma unroll
    for (int cc = 0; cc < 4; cc++) h[cc] = ba1[tid];
    #pragma unroll 2
    for (int j = 0; j < 128; j++){
      float4 wv = wr[j];
      #pragma unroll
      for (int cc = 0; cc < 4; cc++){
        float4 mv = ((const float4*)midc[cc])[j];
        h[cc] += mv.x * wv.x + mv.y * wv.y + mv.z * wv.z + mv.w * wv.w;
      }
    }
    float wa2 = Wa2[tid];
    #pragma unroll
    for (int cc = 0; cc < 4; cc++) hs[cc][tid] = tanhf(h[cc]) * wa2;
  }
  __syncthreads();

  float d0 = Wc[512 + tid] - Wc[tid];
  float d1 = Wc[768 + tid] - Wc[256 + tid];
  for (int cc = 0; cc < 4; cc++){
    red[tid] = midc[cc][tid] * d0 + midc[cc][tid + 256] * d1;
    __syncthreads();
    for (int st = 128; st > 0; st >>= 1){ if (tid < st) red[tid] += red[tid + st]; __syncthreads(); }
    if (tid == 0) tshs[cc] = red[0];
    __syncthreads();
  }
  float maxl = maxlw[g];
  for (int cc = 0; cc < 4; cc++){
    red[tid] = (tid < 128) ? hs[cc][tid] : 0.f;
    __syncthreads();
    for (int st = 128; st > 0; st >>= 1){ if (tid < st) red[tid] += red[tid + st]; __syncthreads(); }
    if (tid == 0){
      float lval = red[0] + ba2[0];
      ekey[c0 + cc] = expf(lval - maxl) * tshs[cc];
    }
    __syncthreads();
  }
}

// ---------------- weighted bag-sum: 64 segments x 8 groups, 16B/lane ----------------
__global__ __launch_bounds__(256) void kbag(const unsigned short* __restrict__ midb,
                                            const float* __restrict__ w,
                                            float* __restrict__ bagp){
  __shared__ float wl[SEGB];
  __shared__ float red[4][512];
  int g = blockIdx.x >> 6, seg = blockIdx.x & 63, tid = threadIdx.x;
  int rg = tid >> 6, lane = tid & 63;
  int i0 = seg * SEGB;
  int nr = GROUP_SIZE - i0; if (nr > SEGB) nr = SEGB;
  size_t base = (size_t)g * GROUP_SIZE;
  if (tid < nr) wl[tid] = w[base + i0 + tid];
  __syncthreads();
  float a[8] = {0.f,0.f,0.f,0.f,0.f,0.f,0.f,0.f};
  const unsigned short* mp = midb + (base + i0) * MDIM + lane * 8;
  for (int i = rg; i < nr; i += 4){
    float wi = wl[i];
    u16x8 v = *(const u16x8*)(mp + (size_t)i * MDIM);
    #pragma unroll
    for (int e = 0; e < 8; e++) a[e] += wi * bf2f((unsigned short)v[e]);
  }
  #pragma unroll
  for (int e = 0; e < 8; e++) red[rg][lane * 8 + e] = a[e];
  __syncthreads();
  if (rg == 0){
    float* dst = bagp + (size_t)blockIdx.x * MDIM + lane * 8;
    #pragma unroll
    for (int e = 0; e < 8; e++){
      int c = lane * 8 + e;
      dst[e] = red[0][c] + red[1][c] + red[2][c] + red[3][c];
    }
  }
}

// ---------------- final: exact re-rank, preds, feature copy — FLOAT32 output ----------------
__global__ __launch_bounds__(256) void kfinal(const float* __restrict__ bagp,
                                              const float* __restrict__ Wc,
                                              const float* __restrict__ bc,
                                              const float* __restrict__ emid,
                                              const float* __restrict__ ekey,
                                              const int* __restrict__ cand,
                                              float* __restrict__ out){
  __shared__ float k32[32];
  __shared__ int s32[32];
  __shared__ int ordv[32];
  __shared__ float r0[256], r1[256];
  int g = blockIdx.x, tid = threadIdx.x;
  if (tid < 32){ k32[tid] = ekey[g * 32 + tid]; s32[tid] = cand[g * 32 + tid]; }
  __syncthreads();
  if (tid == 0){
    unsigned used = 0;
    for (int a = 0; a < 32; a++){
      int best = -1;
      for (int b = 0; b < 32; b++){
        if ((used >> b) & 1u) continue;
        if (best < 0 || k32[b] > k32[best] || (k32[b] == k32[best] && s32[b] < s32[best])) best = b;
      }
      used |= 1u << best;
      ordv[a] = best;
    }
  }
  float p0 = 0.f, p1 = 0.f;
  for (int j = tid; j < 512; j += 256){
    float bv = 0.f;
    for (int s2 = 0; s2 < 64; s2++) bv += bagp[(size_t)(g * 64 + s2) * MDIM + j];
    p0 += bv * Wc[j];
    p1 += bv * Wc[512 + j];
  }
  r0[tid] = p0; r1[tid] = p1; __syncthreads();
  for (int s = 128; s > 0; s >>= 1){ if (tid < s){ r0[tid] += r0[tid + s]; r1[tid] += r1[tid + s]; } __syncthreads(); }
  if (tid == 0){
    out[g * 2 + 0] = r0[0] + bc[0];
    out[g * 2 + 1] = r1[0] + bc[1];
  }
  __syncthreads();
  for (int p = 0; p < 8; p++){
    int cc = ordv[p < 4 ? p : 24 + p];
    const float* src = emid + (size_t)(g * 32 + cc) * MDIM;
    float* dst = out + 16 + (size_t)(g * 8 + p) * MDIM;
    for (int j = tid; j < 512; j += 256) dst[j] = src[j];
  }
}

extern "C" void kernel_launch(void* const* d_in, const int* in_sizes, int n_in,
                              void* d_out, int out_size, void* d_ws, size_t ws_size,
                              hipStream_t stream){
  const int*   idxf = (const int*)d_in[0];
  const float* tfeat= (const float*)d_in[1];
  const float* W1   = (const float*)d_in[2];
  const float* b1   = (const float*)d_in[3];
  const float* Wa1  = (const float*)d_in[4];
  const float* ba1  = (const float*)d_in[5];
  const float* Wa2  = (const float*)d_in[6];
  const float* ba2  = (const float*)d_in[7];
  const float* Wc   = (const float*)d_in[8];
  const float* bc   = (const float*)d_in[9];
  float* out = (float*)d_out;
  (void)in_sizes; (void)n_in; (void)out_size; (void)ws_size;

  char* ws = (char*)d_ws;
  size_t off = 0;
  auto alloc = [&](size_t bytes){ void* p = ws + off; off += (bytes + 255) & ~(size_t)255; return p; };
  float* lv    = (float*)alloc((size_t)N_TOT * 4);
  float* tvp   = (float*)alloc((size_t)2 * N_TOT * 4);
  float* wsm   = (float*)alloc((size_t)N_TOT * 4);
  float* maxlw = (float*)alloc(NUM_GROUP * 4);
  float* Zw    = (float*)alloc(NUM_GROUP * 4);
  int*   cand  = (int*)alloc(NUM_GROUP * 32 * 4);
  float* ekey  = (float*)alloc(NUM_GROUP * 32 * 4);
  float* ptk   = (float*)alloc(64 * 16 * 4);
  int*   pti   = (int*)alloc(64 * 16 * 4);
  float* pbk   = (float*)alloc(64 * 16 * 4);
  int*   pbi   = (int*)alloc(64 * 16 * 4);
  float* emid  = (float*)alloc((size_t)NUM_GROUP * 32 * MDIM * 4);
  float* bagp  = (float*)alloc((size_t)NUM_GROUP * 64 * MDIM * 4);
  unsigned short* W1b  = (unsigned short*)alloc((size_t)MDIM * IN_CHN * 2);
  unsigned short* Wa1b = (unsigned short*)alloc((size_t)ATT_D * MDIM * 2);
  unsigned short* midb = (unsigned short*)alloc((size_t)N_TOT * MDIM * 2);

  kconv<<<2304, 256, 0, stream>>>(W1, Wa1, W1b, Wa1b);
  kgemm_mid<<<1564, 512, 0, stream>>>(idxf, tfeat, W1b, b1, Wc, midb, tvp);
  kattn<<<1563, 256, 0, stream>>>(midb, Wa1b, ba1, Wa2, ba2, lv);
  kstat<<<8, 256, 0, stream>>>(lv, maxlw, Zw, wsm);
  kpsel<<<64, 256, 0, stream>>>(wsm, tvp, ptk, pti, pbk, pbi);
  kmerge<<<8, 256, 0, stream>>>(ptk, pti, pbk, pbi, cand);
  kexact<<<64, 256, 0, stream>>>(idxf, tfeat, W1, b1, Wa1, ba1, Wa2, ba2, Wc, cand, maxlw, emid, ekey);
  kbag<<<512, 256, 0, stream>>>(midb, wsm, bagp);
  kfinal<<<8, 256, 0, stream>>>(bagp, Wc, bc, emid, ekey, cand, out);
}